// Round 2
// baseline (485.117 us; speedup 1.0000x reference)
//
#include <hip/hip_runtime.h>
#include <math.h>

#define ALPHA 0.2f
#define NEGV  -9e15f
#define EPSV  1e-5f

constexpr int B_ = 2, N_ = 4096, F_ = 256, H_ = 1024;
constexpr int SPLIT_ = 16;   // colstats i-split

typedef __attribute__((ext_vector_type(4))) float f32x4;
typedef __attribute__((ext_vector_type(8))) short s16x8;

__device__ __forceinline__ unsigned short f2bf(float f) {
    unsigned u = __builtin_bit_cast(unsigned, f);
    u += 0x7fffu + ((u >> 16) & 1u);
    return (unsigned short)(u >> 16);
}

// ---------------- zero scratch for Wh1/Wh2 atomics -----------------------------
__global__ __launch_bounds__(256) void zero_kernel(float* __restrict__ p)
{
    const int i = (blockIdx.x * 256 + threadIdx.x) * 4;
    *(float4*)&p[i] = make_float4(0.f, 0.f, 0.f, 0.f);
}

// ---------------- batched weight transpose + bf16: src[R][C] -> dst[C][R] ------
__global__ __launch_bounds__(256) void transp_all_kernel(
    const float* __restrict__ W1, const float* __restrict__ W2,
    const float* __restrict__ F1s, const float* __restrict__ F2s,
    unsigned short* __restrict__ D1, unsigned short* __restrict__ D2,
    unsigned short* __restrict__ D3, unsigned short* __restrict__ D4)
{
    const int mi = blockIdx.z;
    const float* src; unsigned short* dst; int R, Cc;
    if (mi == 0)      { src = W1;  dst = D1; R = 256;  Cc = 256; }
    else if (mi == 1) { src = W2;  dst = D2; R = 256;  Cc = 256; }
    else if (mi == 2) { src = F1s; dst = D3; R = 256;  Cc = 1024; }
    else              { src = F2s; dst = D4; R = 1024; Cc = 256; }
    const int r0 = blockIdx.x * 64, c0 = blockIdx.y * 64;
    if (r0 >= R || c0 >= Cc) return;

    __shared__ float T[64][65];
    const int t = threadIdx.x;
    #pragma unroll
    for (int s = 0; s < 4; ++s) {
        const int rr = s * 16 + (t >> 4);
        const int cq = t & 15;
        const float4 v = *(const float4*)&src[(size_t)(r0 + rr) * Cc + c0 + cq * 4];
        T[rr][cq * 4 + 0] = v.x; T[rr][cq * 4 + 1] = v.y;
        T[rr][cq * 4 + 2] = v.z; T[rr][cq * 4 + 3] = v.w;
    }
    __syncthreads();
    #pragma unroll
    for (int s = 0; s < 4; ++s) {
        const int cr = s * 16 + (t >> 4);
        const int rq = t & 15;
        ushort4 o;
        o.x = f2bf(T[rq * 4 + 0][cr]);
        o.y = f2bf(T[rq * 4 + 1][cr]);
        o.z = f2bf(T[rq * 4 + 2][cr]);
        o.w = f2bf(T[rq * 4 + 3][cr]);
        *(ushort4*)&dst[(size_t)(c0 + cr) * R + r0 + rq * 4] = o;
    }
}

// ---------------- 128x128 bf16 MFMA GEMM (used for FFN1: 512 blocks) -----------
__global__ __launch_bounds__(256) void gemm128_kernel(
    const void* __restrict__ Ap, const unsigned short* __restrict__ Wt,
    const float* __restrict__ bias, void* __restrict__ Cp,
    unsigned short* __restrict__ Tout, const float* __restrict__ wha,
    float* __restrict__ Wh1, float* __restrict__ Wh2,
    int Nc, int K, int relu, int a_bf16, int c_mode)
{
    __shared__ unsigned short As[128 * 72];
    __shared__ unsigned short Bs[128 * 72];
    const int t = threadIdx.x;
    const int w = t >> 6, l = t & 63;
    const int quad = l >> 4, l15 = l & 15;
    const int wr = w & 1, wc = w >> 1;
    const int row0 = blockIdx.y * 128, col0 = blockIdx.x * 128;
    const int sr = t >> 1;           // 0..127
    const int sk = (t & 1) * 32;     // 0 or 32

    f32x4 acc[4][4];
    #pragma unroll
    for (int it = 0; it < 4; ++it)
        #pragma unroll
        for (int ft = 0; ft < 4; ++ft) acc[it][ft] = (f32x4)(0.f);

    for (int k0 = 0; k0 < K; k0 += 64) {
        if (a_bf16) {
            const unsigned short* ap =
                (const unsigned short*)Ap + (size_t)(row0 + sr) * K + k0 + sk;
            #pragma unroll
            for (int u = 0; u < 4; ++u)
                *(s16x8*)&As[sr * 72 + sk + u * 8] = *(const s16x8*)(ap + u * 8);
        } else {
            const float* ap = (const float*)Ap + (size_t)(row0 + sr) * K + k0 + sk;
            #pragma unroll
            for (int u = 0; u < 8; ++u) {
                const float4 v = *(const float4*)(ap + u * 4);
                ushort4 o;
                o.x = f2bf(v.x); o.y = f2bf(v.y); o.z = f2bf(v.z); o.w = f2bf(v.w);
                *(ushort4*)&As[sr * 72 + sk + u * 4] = o;
            }
        }
        {
            const unsigned short* bp = Wt + (size_t)(col0 + sr) * K + k0 + sk;
            #pragma unroll
            for (int u = 0; u < 4; ++u)
                *(s16x8*)&Bs[sr * 72 + sk + u * 8] = *(const s16x8*)(bp + u * 8);
        }
        __syncthreads();
        #pragma unroll
        for (int ks = 0; ks < 64; ks += 32) {
            s16x8 af[4], bf[4];
            #pragma unroll
            for (int it = 0; it < 4; ++it)
                af[it] = *(const s16x8*)&As[(wr * 64 + it * 16 + l15) * 72 + ks + quad * 8];
            #pragma unroll
            for (int ft = 0; ft < 4; ++ft)
                bf[ft] = *(const s16x8*)&Bs[(wc * 64 + ft * 16 + l15) * 72 + ks + quad * 8];
            #pragma unroll
            for (int ft = 0; ft < 4; ++ft)
                #pragma unroll
                for (int it = 0; it < 4; ++it)
                    acc[it][ft] = __builtin_amdgcn_mfma_f32_16x16x32_bf16(
                        af[it], bf[ft], acc[it][ft], 0, 0, 0);
        }
        __syncthreads();
    }

    if (c_mode) {
        #pragma unroll
        for (int ft = 0; ft < 4; ++ft) {
            const int col = col0 + wc * 64 + ft * 16 + l15;
            const float bv = bias ? bias[col] : 0.f;
            #pragma unroll
            for (int it = 0; it < 4; ++it) {
                const int rbase = row0 + wr * 64 + it * 16 + quad * 4;
                #pragma unroll
                for (int rr = 0; rr < 4; ++rr) {
                    float v = acc[it][ft][rr] + bv;
                    if (relu) v = fmaxf(v, 0.f);
                    if (c_mode == 2)
                        ((unsigned short*)Cp)[(size_t)(rbase + rr) * Nc + col] = f2bf(v);
                    else
                        ((float*)Cp)[(size_t)(rbase + rr) * Nc + col] = v;
                }
            }
        }
    }

    if (Tout) {
        const int bb = row0 >> 12;
        #pragma unroll
        for (int ft = 0; ft < 4; ++ft) {
            const int col = col0 + wc * 64 + ft * 16 + l15;
            #pragma unroll
            for (int it = 0; it < 4; ++it) {
                const int ibase = (row0 & (N_ - 1)) + wr * 64 + it * 16 + quad * 4;
                ushort4 o;
                o.x = f2bf(acc[it][ft][0]); o.y = f2bf(acc[it][ft][1]);
                o.z = f2bf(acc[it][ft][2]); o.w = f2bf(acc[it][ft][3]);
                *(ushort4*)&Tout[((size_t)bb * F_ + col) * N_ + ibase] = o;
            }
        }
    }

    if (wha) {
        float a1v[4], a2v[4];
        #pragma unroll
        for (int ft = 0; ft < 4; ++ft) {
            const int col = col0 + wc * 64 + ft * 16 + l15;
            a1v[ft] = wha[col];
            a2v[ft] = wha[F_ + col];
        }
        #pragma unroll
        for (int it = 0; it < 4; ++it)
            #pragma unroll
            for (int rr = 0; rr < 4; ++rr) {
                float s1 = 0.f, s2 = 0.f;
                #pragma unroll
                for (int ft = 0; ft < 4; ++ft) {
                    s1 += acc[it][ft][rr] * a1v[ft];
                    s2 += acc[it][ft][rr] * a2v[ft];
                }
                #pragma unroll
                for (int mkk = 1; mkk < 16; mkk <<= 1) {
                    s1 += __shfl_xor(s1, mkk);
                    s2 += __shfl_xor(s2, mkk);
                }
                if (l15 == 0) {
                    const int row = row0 + wr * 64 + it * 16 + quad * 4 + rr;
                    atomicAdd(&Wh1[row], s1);
                    atomicAdd(&Wh2[row], s2);
                }
            }
    }
}

// ---------------- 64x128 bf16 MFMA GEMM (256 blocks -> full CU coverage) -------
__global__ __launch_bounds__(256) void gemm64_kernel(
    const void* __restrict__ Ap, const unsigned short* __restrict__ Wt,
    const float* __restrict__ bias, void* __restrict__ Cp,
    unsigned short* __restrict__ Tout, const float* __restrict__ wha,
    float* __restrict__ Wh1, float* __restrict__ Wh2,
    int Nc, int K, int relu, int a_bf16, int c_mode)
{
    __shared__ unsigned short As[64 * 72];
    __shared__ unsigned short Bs[128 * 72];
    const int t = threadIdx.x;
    const int w = t >> 6, l = t & 63;
    const int quad = l >> 4, l15 = l & 15;
    const int row0 = blockIdx.y * 64, col0 = blockIdx.x * 128;
    const int sra = t >> 2;            // 0..63
    const int ska = (t & 3) * 16;      // 0,16,32,48
    const int srb = t >> 1;            // 0..127
    const int skb = (t & 1) * 32;      // 0 or 32

    f32x4 acc[4][2];
    #pragma unroll
    for (int it = 0; it < 4; ++it)
        #pragma unroll
        for (int ft = 0; ft < 2; ++ft) acc[it][ft] = (f32x4)(0.f);

    for (int k0 = 0; k0 < K; k0 += 64) {
        if (a_bf16) {
            const unsigned short* ap =
                (const unsigned short*)Ap + (size_t)(row0 + sra) * K + k0 + ska;
            *(s16x8*)&As[sra * 72 + ska]     = *(const s16x8*)ap;
            *(s16x8*)&As[sra * 72 + ska + 8] = *(const s16x8*)(ap + 8);
        } else {
            const float* ap = (const float*)Ap + (size_t)(row0 + sra) * K + k0 + ska;
            #pragma unroll
            for (int u = 0; u < 4; ++u) {
                const float4 v = *(const float4*)(ap + u * 4);
                ushort4 o;
                o.x = f2bf(v.x); o.y = f2bf(v.y); o.z = f2bf(v.z); o.w = f2bf(v.w);
                *(ushort4*)&As[sra * 72 + ska + u * 4] = o;
            }
        }
        {
            const unsigned short* bp = Wt + (size_t)(col0 + srb) * K + k0 + skb;
            #pragma unroll
            for (int u = 0; u < 4; ++u)
                *(s16x8*)&Bs[srb * 72 + skb + u * 8] = *(const s16x8*)(bp + u * 8);
        }
        __syncthreads();
        #pragma unroll
        for (int ks = 0; ks < 64; ks += 32) {
            s16x8 af[4], bf[2];
            #pragma unroll
            for (int it = 0; it < 4; ++it)
                af[it] = *(const s16x8*)&As[(it * 16 + l15) * 72 + ks + quad * 8];
            #pragma unroll
            for (int ft = 0; ft < 2; ++ft)
                bf[ft] = *(const s16x8*)&Bs[(w * 32 + ft * 16 + l15) * 72 + ks + quad * 8];
            #pragma unroll
            for (int ft = 0; ft < 2; ++ft)
                #pragma unroll
                for (int it = 0; it < 4; ++it)
                    acc[it][ft] = __builtin_amdgcn_mfma_f32_16x16x32_bf16(
                        af[it], bf[ft], acc[it][ft], 0, 0, 0);
        }
        __syncthreads();
    }

    if (c_mode) {
        #pragma unroll
        for (int ft = 0; ft < 2; ++ft) {
            const int col = col0 + w * 32 + ft * 16 + l15;
            const float bv = bias ? bias[col] : 0.f;
            #pragma unroll
            for (int it = 0; it < 4; ++it) {
                const int rbase = row0 + it * 16 + quad * 4;
                #pragma unroll
                for (int rr = 0; rr < 4; ++rr) {
                    float v = acc[it][ft][rr] + bv;
                    if (relu) v = fmaxf(v, 0.f);
                    if (c_mode == 2)
                        ((unsigned short*)Cp)[(size_t)(rbase + rr) * Nc + col] = f2bf(v);
                    else
                        ((float*)Cp)[(size_t)(rbase + rr) * Nc + col] = v;
                }
            }
        }
    }

    if (Tout) {
        const int bb = row0 >> 12;
        #pragma unroll
        for (int ft = 0; ft < 2; ++ft) {
            const int col = col0 + w * 32 + ft * 16 + l15;
            #pragma unroll
            for (int it = 0; it < 4; ++it) {
                const int ibase = (row0 & (N_ - 1)) + it * 16 + quad * 4;
                ushort4 o;
                o.x = f2bf(acc[it][ft][0]); o.y = f2bf(acc[it][ft][1]);
                o.z = f2bf(acc[it][ft][2]); o.w = f2bf(acc[it][ft][3]);
                *(ushort4*)&Tout[((size_t)bb * F_ + col) * N_ + ibase] = o;
            }
        }
    }

    if (wha) {
        float a1v[2], a2v[2];
        #pragma unroll
        for (int ft = 0; ft < 2; ++ft) {
            const int col = col0 + w * 32 + ft * 16 + l15;
            a1v[ft] = wha[col];
            a2v[ft] = wha[F_ + col];
        }
        #pragma unroll
        for (int it = 0; it < 4; ++it)
            #pragma unroll
            for (int rr = 0; rr < 4; ++rr) {
                float s1 = acc[it][0][rr] * a1v[0] + acc[it][1][rr] * a1v[1];
                float s2 = acc[it][0][rr] * a2v[0] + acc[it][1][rr] * a2v[1];
                #pragma unroll
                for (int mkk = 1; mkk < 16; mkk <<= 1) {
                    s1 += __shfl_xor(s1, mkk);
                    s2 += __shfl_xor(s2, mkk);
                }
                if (l15 == 0) {
                    const int row = row0 + it * 16 + quad * 4 + rr;
                    atomicAdd(&Wh1[row], s1);
                    atomicAdd(&Wh2[row], s2);
                }
            }
    }
}

// ---------------- layer-1: adj -> stats + bitmask (fused, 8-wide ILP) ----------
__global__ __launch_bounds__(256) void colstats_adj_kernel(
    const int* __restrict__ adj, unsigned long long* __restrict__ maskOut,
    const float* __restrict__ Wh1, const float* __restrict__ Wh2,
    float* __restrict__ pM, float* __restrict__ pS)
{
    const int t = threadIdx.x;
    const int j = blockIdx.x * 256 + t;
    const int sp = blockIdx.y;
    const int b = blockIdx.z;
    const int i0 = sp * (N_ / SPLIT_);
    const int w = t >> 6, l = t & 63;
    const float w2 = Wh2[b * N_ + j];
    const float* __restrict__ w1p = Wh1 + b * N_ + i0;
    const int* __restrict__ ap = adj + ((size_t)b * N_ + i0) * N_ + j;

    float m = -3.4e38f, s = 0.f;
    for (int c = 0; c < N_ / SPLIT_; c += 8) {
        int v[8];
        #pragma unroll
        for (int u = 0; u < 8; ++u) v[u] = ap[(size_t)(c + u) * N_];
        float x[8];
        #pragma unroll
        for (int u = 0; u < 8; ++u) {
            const bool act = v[u] > 0;
            const unsigned long long bm = __ballot(act);
            if (l == 0)
                maskOut[((size_t)b * N_ + i0 + c + u) * (N_ / 64) + blockIdx.x * 4 + w] = bm;
            const float e0 = w1p[c + u] + w2;
            const float e = fmaxf(e0, ALPHA * e0);
            x[u] = act ? e : NEGV;
        }
        const float cm = fmaxf(fmaxf(fmaxf(x[0], x[1]), fmaxf(x[2], x[3])),
                               fmaxf(fmaxf(x[4], x[5]), fmaxf(x[6], x[7])));
        const float nm = fmaxf(m, cm);
        float cs = 0.f;
        #pragma unroll
        for (int u = 0; u < 8; ++u) cs += __expf(x[u] - nm);
        s = s * __expf(m - nm) + cs;
        m = nm;
    }
    pM[((size_t)b * SPLIT_ + sp) * N_ + j] = m;
    pS[((size_t)b * SPLIT_ + sp) * N_ + j] = s;
}

// ---------------- layer-2: stats from bitmask ----------------------------------
__global__ __launch_bounds__(256) void colstats3_kernel(
    const unsigned long long* __restrict__ mask,
    const float* __restrict__ Wh1, const float* __restrict__ Wh2,
    float* __restrict__ pM, float* __restrict__ pS)
{
    const int t = threadIdx.x;
    const int j = blockIdx.x * 256 + t;
    const int sp = blockIdx.y;
    const int b = blockIdx.z;
    const int i0 = sp * (N_ / SPLIT_);
    const int w = t >> 6;
    const int jbit = t & 63;
    const float w2 = Wh2[b * N_ + j];
    const unsigned long long* __restrict__ mbase =
        mask + ((size_t)b * N_ + i0) * (N_ / 64) + blockIdx.x * 4 + w;
    const float* __restrict__ w1p = Wh1 + b * N_ + i0;

    float m = -3.4e38f, s = 0.f;
    for (int c = 0; c < N_ / SPLIT_; c += 8) {
        float x[8];
        #pragma unroll
        for (int u = 0; u < 8; ++u) {
            const unsigned long long mw = mbase[(size_t)(c + u) * (N_ / 64)];
            const float e0 = w1p[c + u] + w2;
            const float e = fmaxf(e0, ALPHA * e0);
            x[u] = ((mw >> jbit) & 1ull) ? e : NEGV;
        }
        const float cm = fmaxf(fmaxf(fmaxf(x[0], x[1]), fmaxf(x[2], x[3])),
                               fmaxf(fmaxf(x[4], x[5]), fmaxf(x[6], x[7])));
        const float nm = fmaxf(m, cm);
        float cs = 0.f;
        #pragma unroll
        for (int u = 0; u < 8; ++u) cs += __expf(x[u] - nm);
        s = s * __expf(m - nm) + cs;
        m = nm;
    }
    pM[((size_t)b * SPLIT_ + sp) * N_ + j] = m;
    pS[((size_t)b * SPLIT_ + sp) * N_ + j] = s;
}

// ---------------- finalize: mo = m + ln(sum) -----------------------------------
__global__ __launch_bounds__(256) void colfin2_kernel(
    const float* __restrict__ pM, const float* __restrict__ pS,
    float* __restrict__ Mo)
{
    const int j = blockIdx.x * 256 + threadIdx.x;
    const int b = blockIdx.y;
    float m = -3.4e38f;
    #pragma unroll
    for (int s = 0; s < SPLIT_; ++s)
        m = fmaxf(m, pM[((size_t)b * SPLIT_ + s) * N_ + j]);
    float sum = 0.f;
    #pragma unroll
    for (int s = 0; s < SPLIT_; ++s)
        sum += pS[((size_t)b * SPLIT_ + s) * N_ + j] *
               __expf(pM[((size_t)b * SPLIT_ + s) * N_ + j] - m);
    Mo[b * N_ + j] = m + logf(sum);
}

// ---------------- attention v5: full j-sweep per block, direct output ----------
// Grid 256 blocks x 512 thr (8 waves). i-tile = 32 rows, full F=256 cols.
// No j-split -> NO partial buffer: layer1 writes bf16 [row][F] (g1b) directly,
// layer2 writes fp32 attout. B frags direct from L2-resident Wht (dbuf in regs),
// P double-buffered in LDS (one barrier per 64-j step). XCD remap pins batch b
// to an XCD group so each XCD L2 caches one 2MB Wht slice.
__global__ __launch_bounds__(512) void att_mfma5_kernel(
    const unsigned short* __restrict__ mask16, const unsigned short* __restrict__ Wht,
    const float* __restrict__ Wh1, const float* __restrict__ Wh2,
    const float* __restrict__ Mo, unsigned short* __restrict__ outb,
    float* __restrict__ outf)
{
    __shared__ unsigned short Ps[2][32 * 72];
    __shared__ float w2s[N_];
    __shared__ float mos[N_];

    const int t = threadIdx.x;
    const int w = t >> 6, l = t & 63;
    const int quad = l >> 4, l15 = l & 15;

    // bijective remap: 256 blocks; default rr dispatch -> xcd = lin&7.
    const int lin = blockIdx.x;
    const int xcd = lin & 7;
    const int b = xcd >> 2;                       // b pinned to XCD group
    const int tile = (lin >> 3) * 4 + (xcd & 3);  // 0..127
    const int i0 = tile * 32;

    const int pi = t >> 4;      // P row 0..31
    const int pj = t & 15;      // j-quad group: j-offset pj*4 within 64-step
    const float w1i = Wh1[b * N_ + i0 + pi];
    const unsigned short* __restrict__ mrow =
        mask16 + ((size_t)b * N_ + i0 + pi) * (N_ / 16);
    const unsigned short* __restrict__ WhtB = Wht + (size_t)b * F_ * N_;

    {   // stage full Wh2/Mo rows (4096 each)
        const float4 a0 = *(const float4*)&Wh2[b * N_ + t * 8];
        const float4 a1 = *(const float4*)&Wh2[b * N_ + t * 8 + 4];
        const float4 c0 = *(const float4*)&Mo[b * N_ + t * 8];
        const float4 c1 = *(const float4*)&Mo[b * N_ + t * 8 + 4];
        *(float4*)&w2s[t * 8] = a0; *(float4*)&w2s[t * 8 + 4] = a1;
        *(float4*)&mos[t * 8] = c0; *(float4*)&mos[t * 8 + 4] = c1;
    }

    f32x4 acc[2][2];
    #pragma unroll
    for (int it = 0; it < 2; ++it)
        #pragma unroll
        for (int ft = 0; ft < 2; ++ft) acc[it][ft] = (f32x4)(0.f);

    // wave w covers output cols [w*32, w*32+32)
    const unsigned short* __restrict__ bbase =
        WhtB + (size_t)(w * 32 + l15) * N_ + quad * 8;

    s16x8 bA[4], bB[4];

    auto prefB = [&](int itr2, s16x8* dst) {
        const unsigned short* nb = bbase + itr2 * 64;
        #pragma unroll
        for (int ft = 0; ft < 2; ++ft)
            #pragma unroll
            for (int kk = 0; kk < 2; ++kk)
                dst[ft * 2 + kk] = *(const s16x8*)&nb[(size_t)ft * 16 * N_ + kk * 32];
    };

    auto computeP = [&](int itr2, unsigned short* psdst) {
        const unsigned mb = mrow[itr2 * 4 + (pj >> 2)];
        const int bsh = (pj & 3) * 4;
        const int jl = itr2 * 64 + pj * 4;
        const float4 w2v = *(const float4*)&w2s[jl];
        const float4 mov = *(const float4*)&mos[jl];
        ushort4 o;
        unsigned short* op = &o.x;
        #pragma unroll
        for (int u = 0; u < 4; ++u) {
            const float xw = w1i + (&w2v.x)[u];
            const float e = fmaxf(xw, ALPHA * xw);
            const float x2 = ((mb >> (bsh + u)) & 1u) ? e : NEGV;
            op[u] = f2bf(__expf(x2 - (&mov.x)[u]));
        }
        *(ushort4*)&psdst[pi * 72 + pj * 4] = o;
    };

    auto mfmaStep = [&](const unsigned short* ps, const s16x8* breg) {
        #pragma unroll
        for (int ksidx = 0; ksidx < 2; ++ksidx) {
            s16x8 af[2];
            #pragma unroll
            for (int it = 0; it < 2; ++it)
                af[it] = *(const s16x8*)&ps[(it * 16 + l15) * 72 + ksidx * 32 + quad * 8];
            #pragma unroll
            for (int ft = 0; ft < 2; ++ft)
                #pragma unroll
                for (int it = 0; it < 2; ++it)
                    acc[it][ft] = __builtin_amdgcn_mfma_f32_16x16x32_bf16(
                        af[it], breg[ft * 2 + ksidx], acc[it][ft], 0, 0, 0);
        }
    };

    prefB(0, bA);
    __syncthreads();            // w2s/mos ready
    computeP(0, &Ps[0][0]);
    __syncthreads();            // Ps[0] ready

    constexpr int NITER = N_ / 64;   // 64 (even)
    for (int itr = 0; itr < NITER; itr += 2) {
        prefB(itr + 1, bB);
        computeP(itr + 1, &Ps[1][0]);
        mfmaStep(&Ps[0][0], bA);
        __syncthreads();
        if (itr + 2 < NITER) {
            prefB(itr + 2, bA);
            computeP(itr + 2, &Ps[0][0]);
        }
        mfmaStep(&Ps[1][0], bB);
        __syncthreads();
    }

    if (outb) {
        unsigned short* __restrict__ ob = outb + (size_t)(b * N_ + i0) * F_;
        #pragma unroll
        for (int it = 0; it < 2; ++it)
            #pragma unroll
            for (int ft = 0; ft < 2; ++ft) {
                const int col = w * 32 + ft * 16 + l15;
                #pragma unroll
                for (int rr = 0; rr < 4; ++rr)
                    ob[(size_t)(it * 16 + quad * 4 + rr) * F_ + col] =
                        f2bf(acc[it][ft][rr]);
            }
    } else {
        float* __restrict__ of = outf + (size_t)(b * N_ + i0) * F_;
        #pragma unroll
        for (int it = 0; it < 2; ++it)
            #pragma unroll
            for (int ft = 0; ft < 2; ++ft) {
                const int col = w * 32 + ft * 16 + l15;
                #pragma unroll
                for (int rr = 0; rr < 4; ++rr)
                    of[(size_t)(it * 16 + quad * 4 + rr) * F_ + col] =
                        acc[it][ft][rr];
            }
    }
}

// ---------------- x + attout + LayerNorm -> fp32 + bf16 ------------------------
__global__ __launch_bounds__(256) void addln2b_kernel(
    const float* __restrict__ X, const float* __restrict__ Y,
    const float* __restrict__ g, const float* __restrict__ bta,
    float* __restrict__ outf, unsigned short* __restrict__ outb)
{
    const int row = blockIdx.x;
    const int t = threadIdx.x;
    const size_t idx = (size_t)row * F_ + t;
    const float v = X[idx] + Y[idx];
    float s1 = v, s2 = v * v;
    #pragma unroll
    for (int off = 32; off > 0; off >>= 1) {
        s1 += __shfl_down(s1, off);
        s2 += __shfl_down(s2, off);
    }
    __shared__ float r1[4], r2[4];
    __shared__ float mu_s, rs_s;
    const int wid = t >> 6, lane = t & 63;
    if (lane == 0) { r1[wid] = s1; r2[wid] = s2; }
    __syncthreads();
    if (t == 0) {
        const float a = r1[0] + r1[1] + r1[2] + r1[3];
        const float q = r2[0] + r2[1] + r2[2] + r2[3];
        const float mu = a * (1.f / F_);
        const float var = q * (1.f / F_) - mu * mu;
        mu_s = mu;
        rs_s = rsqrtf(var + EPSV);
    }
    __syncthreads();
    const float r = (v - mu_s) * rs_s * g[t] + bta[t];
    outf[idx] = r;
    outb[idx] = f2bf(r);
}

// ---------------- residual add + LayerNorm (final) -----------------------------
__global__ __launch_bounds__(256) void addln_kernel(
    const float* __restrict__ X, const float* __restrict__ Y,
    const float* __restrict__ g, const float* __restrict__ bta,
    float* __restrict__ out)
{
    const int row = blockIdx.x;
    const int t = threadIdx.x;
    const size_t idx = (size_t)row * F_ + t;
    const float v = X[idx] + Y[idx];
    float s1 = v, s2 = v * v;
    #pragma unroll
    for (int off = 32; off > 0; off >>= 1) {
        s1 += __shfl_down(s1, off);
        s2 += __shfl_down(s2, off);
    }
    __shared__ float r1[4], r2[4];
    __shared__ float mu_s, rs_s;
    const int wid = t >> 6, lane = t & 63;
    if (lane == 0) { r1[wid] = s1; r2[wid] = s2; }
    __syncthreads();
    if (t == 0) {
        const float a = r1[0] + r1[1] + r1[2] + r1[3];
        const float q = r2[0] + r2[1] + r2[2] + r2[3];
        const float mu = a * (1.f / F_);
        const float var = q * (1.f / F_) - mu * mu;
        mu_s = mu;
        rs_s = rsqrtf(var + EPSV);
    }
    __syncthreads();
    out[idx] = (v - mu_s) * rs_s * g[t] + bta[t];
}

// -------------------------------------------------------------------------------
extern "C" void kernel_launch(void* const* d_in, const int* in_sizes, int n_in,
                              void* d_out, int out_size, void* d_ws, size_t ws_size,
                              hipStream_t stream)
{
    const float* x     = (const float*)d_in[0];
    const int*   adj   = (const int*)d_in[1];
    const float* W1    = (const float*)d_in[2];
    const float* a1    = (const float*)d_in[3];
    const float* W2    = (const float*)d_in[4];
    const float* a2    = (const float*)d_in[5];
    const float* w_ff1 = (const float*)d_in[6];
    const float* b_ff1 = (const float*)d_in[7];
    const float* w_ff2 = (const float*)d_in[8];
    const float* b_ff2 = (const float*)d_in[9];
    const float* g_ln1 = (const float*)d_in[10];
    const float* b_ln1 = (const float*)d_in[11];
    const float* g_ln2 = (const float*)d_in[12];
    const float* b_ln2 = (const float*)d_in[13];
    float* out = (float*)d_out;

    const int Rtot = B_ * N_;             // 8192
    char* wsb = (char*)d_ws;
    float* attout = (float*)wsb;                                 // 8 MB (was part)
    float* ln1   = (float*)(wsb + 33554432);                     // 8 MB
    float* ffout = (float*)(wsb + 41943040);                     // 8 MB
    unsigned short* mid  = (unsigned short*)(wsb + 50331648);    // 16 MB
    unsigned short* ln1b = (unsigned short*)(wsb + 67108864);    // 4 MB
    unsigned short* g1b  = (unsigned short*)(wsb + 71303168);    // 4 MB
    unsigned short* Wht  = (unsigned short*)(wsb + 75497472);    // 4 MB
    unsigned long long* mask = (unsigned long long*)(wsb + 79691776); // 4 MB
    unsigned short* mask16 = (unsigned short*)mask;
    unsigned short* Wt1  = (unsigned short*)(wsb + 83886080);    // 128 KB
    unsigned short* Wt2  = Wt1 + 65536;                          // 128 KB
    unsigned short* Wtf1 = Wt2 + 65536;                          // 512 KB
    unsigned short* Wtf2 = Wtf1 + 262144;                        // 512 KB
    float* WhA1 = (float*)(wsb + 85196800);
    float* WhA2 = WhA1 + 8192;
    float* WhB1 = WhA2 + 8192;
    float* WhB2 = WhB1 + 8192;
    float* Mo   = (float*)(wsb + 85327872);                      // 32 KB
    float* pM   = (float*)(wsb + 85360640);                      // 512 KB
    float* pS   = (float*)(wsb + 85884928);                      // 512 KB

    const dim3 statsG(N_ / 256, SPLIT_, B_);
    const dim3 finG(N_ / 256, B_);

    // ===== prologue: zero atomic targets, transpose all weights =====
    zero_kernel<<<32, 256, 0, stream>>>(WhA1);   // covers WhA1..WhB2 (32768 f)
    transp_all_kernel<<<dim3(16, 16, 4), 256, 0, stream>>>(
        W1, W2, w_ff1, w_ff2, Wt1, Wt2, Wtf1, Wtf2);

    // ===== GAT layer 1 =====
    gemm64_kernel<<<dim3(2, 128), 256, 0, stream>>>(
        x, Wt1, nullptr, nullptr, Wht, a1, WhA1, WhA2, F_, F_, 0, 0, 0);
    colstats_adj_kernel<<<statsG, 256, 0, stream>>>(adj, mask, WhA1, WhA2, pM, pS);
    colfin2_kernel<<<finG, 256, 0, stream>>>(pM, pS, Mo);
    att_mfma5_kernel<<<256, 512, 0, stream>>>(
        mask16, Wht, WhA1, WhA2, Mo, g1b, nullptr);

    // ===== GAT layer 2 (mask reused) =====
    gemm64_kernel<<<dim3(2, 128), 256, 0, stream>>>(
        g1b, Wt2, nullptr, nullptr, Wht, a2, WhB1, WhB2, F_, F_, 0, 1, 0);
    colstats3_kernel<<<statsG, 256, 0, stream>>>(mask, WhB1, WhB2, pM, pS);
    colfin2_kernel<<<finG, 256, 0, stream>>>(pM, pS, Mo);
    att_mfma5_kernel<<<256, 512, 0, stream>>>(
        mask16, Wht, WhB1, WhB2, Mo, nullptr, attout);

    // ===== LN1(x + attout) -> ln1 fp32 + ln1b bf16 =====
    addln2b_kernel<<<Rtot, 256, 0, stream>>>(x, attout, g_ln1, b_ln1, ln1, ln1b);

    // ===== FFN =====
    gemm128_kernel<<<dim3(8, 64), 256, 0, stream>>>(
        ln1b, Wtf1, b_ff1, mid, nullptr, nullptr, nullptr, nullptr, H_, F_, 1, 1, 2);
    gemm64_kernel<<<dim3(2, 128), 256, 0, stream>>>(
        mid, Wtf2, b_ff2, ffout, nullptr, nullptr, nullptr, nullptr, F_, H_, 0, 1, 1);

    // ===== LN2(ln1 + ff) =====
    addln_kernel<<<Rtot, 256, 0, stream>>>(ln1, ffout, g_ln2, b_ln2, out);
}

// Round 3
// 452.328 us; speedup vs baseline: 1.0725x; 1.0725x over previous
//
#include <hip/hip_runtime.h>
#include <math.h>

#define ALPHA 0.2f
#define NEGV  -9e15f
#define EPSV  1e-5f

constexpr int B_ = 2, N_ = 4096, F_ = 256, H_ = 1024;
constexpr int SPLIT_ = 16;   // colstats i-split

typedef __attribute__((ext_vector_type(4))) float f32x4;
typedef __attribute__((ext_vector_type(8))) short s16x8;

__device__ __forceinline__ unsigned short f2bf(float f) {
    unsigned u = __builtin_bit_cast(unsigned, f);
    u += 0x7fffu + ((u >> 16) & 1u);
    return (unsigned short)(u >> 16);
}

// ---------------- zero scratch for Wh1/Wh2 atomics -----------------------------
__global__ __launch_bounds__(256) void zero_kernel(float* __restrict__ p)
{
    const int i = (blockIdx.x * 256 + threadIdx.x) * 4;
    *(float4*)&p[i] = make_float4(0.f, 0.f, 0.f, 0.f);
}

// ---------------- batched weight transpose + bf16: src[R][C] -> dst[C][R] ------
__global__ __launch_bounds__(256) void transp_all_kernel(
    const float* __restrict__ W1, const float* __restrict__ W2,
    const float* __restrict__ F1s, const float* __restrict__ F2s,
    unsigned short* __restrict__ D1, unsigned short* __restrict__ D2,
    unsigned short* __restrict__ D3, unsigned short* __restrict__ D4)
{
    const int mi = blockIdx.z;
    const float* src; unsigned short* dst; int R, Cc;
    if (mi == 0)      { src = W1;  dst = D1; R = 256;  Cc = 256; }
    else if (mi == 1) { src = W2;  dst = D2; R = 256;  Cc = 256; }
    else if (mi == 2) { src = F1s; dst = D3; R = 256;  Cc = 1024; }
    else              { src = F2s; dst = D4; R = 1024; Cc = 256; }
    const int r0 = blockIdx.x * 64, c0 = blockIdx.y * 64;
    if (r0 >= R || c0 >= Cc) return;

    __shared__ float T[64][65];
    const int t = threadIdx.x;
    #pragma unroll
    for (int s = 0; s < 4; ++s) {
        const int rr = s * 16 + (t >> 4);
        const int cq = t & 15;
        const float4 v = *(const float4*)&src[(size_t)(r0 + rr) * Cc + c0 + cq * 4];
        T[rr][cq * 4 + 0] = v.x; T[rr][cq * 4 + 1] = v.y;
        T[rr][cq * 4 + 2] = v.z; T[rr][cq * 4 + 3] = v.w;
    }
    __syncthreads();
    #pragma unroll
    for (int s = 0; s < 4; ++s) {
        const int cr = s * 16 + (t >> 4);
        const int rq = t & 15;
        ushort4 o;
        o.x = f2bf(T[rq * 4 + 0][cr]);
        o.y = f2bf(T[rq * 4 + 1][cr]);
        o.z = f2bf(T[rq * 4 + 2][cr]);
        o.w = f2bf(T[rq * 4 + 3][cr]);
        *(ushort4*)&dst[(size_t)(c0 + cr) * R + r0 + rq * 4] = o;
    }
}

// ---------------- 128x128 bf16 MFMA GEMM (used for FFN1: 512 blocks) -----------
__global__ __launch_bounds__(256) void gemm128_kernel(
    const void* __restrict__ Ap, const unsigned short* __restrict__ Wt,
    const float* __restrict__ bias, void* __restrict__ Cp,
    unsigned short* __restrict__ Tout, const float* __restrict__ wha,
    float* __restrict__ Wh1, float* __restrict__ Wh2,
    int Nc, int K, int relu, int a_bf16, int c_mode)
{
    __shared__ unsigned short As[128 * 72];
    __shared__ unsigned short Bs[128 * 72];
    const int t = threadIdx.x;
    const int w = t >> 6, l = t & 63;
    const int quad = l >> 4, l15 = l & 15;
    const int wr = w & 1, wc = w >> 1;
    const int row0 = blockIdx.y * 128, col0 = blockIdx.x * 128;
    const int sr = t >> 1;           // 0..127
    const int sk = (t & 1) * 32;     // 0 or 32

    f32x4 acc[4][4];
    #pragma unroll
    for (int it = 0; it < 4; ++it)
        #pragma unroll
        for (int ft = 0; ft < 4; ++ft) acc[it][ft] = (f32x4)(0.f);

    for (int k0 = 0; k0 < K; k0 += 64) {
        if (a_bf16) {
            const unsigned short* ap =
                (const unsigned short*)Ap + (size_t)(row0 + sr) * K + k0 + sk;
            #pragma unroll
            for (int u = 0; u < 4; ++u)
                *(s16x8*)&As[sr * 72 + sk + u * 8] = *(const s16x8*)(ap + u * 8);
        } else {
            const float* ap = (const float*)Ap + (size_t)(row0 + sr) * K + k0 + sk;
            #pragma unroll
            for (int u = 0; u < 8; ++u) {
                const float4 v = *(const float4*)(ap + u * 4);
                ushort4 o;
                o.x = f2bf(v.x); o.y = f2bf(v.y); o.z = f2bf(v.z); o.w = f2bf(v.w);
                *(ushort4*)&As[sr * 72 + sk + u * 4] = o;
            }
        }
        {
            const unsigned short* bp = Wt + (size_t)(col0 + sr) * K + k0 + sk;
            #pragma unroll
            for (int u = 0; u < 4; ++u)
                *(s16x8*)&Bs[sr * 72 + sk + u * 8] = *(const s16x8*)(bp + u * 8);
        }
        __syncthreads();
        #pragma unroll
        for (int ks = 0; ks < 64; ks += 32) {
            s16x8 af[4], bf[4];
            #pragma unroll
            for (int it = 0; it < 4; ++it)
                af[it] = *(const s16x8*)&As[(wr * 64 + it * 16 + l15) * 72 + ks + quad * 8];
            #pragma unroll
            for (int ft = 0; ft < 4; ++ft)
                bf[ft] = *(const s16x8*)&Bs[(wc * 64 + ft * 16 + l15) * 72 + ks + quad * 8];
            #pragma unroll
            for (int ft = 0; ft < 4; ++ft)
                #pragma unroll
                for (int it = 0; it < 4; ++it)
                    acc[it][ft] = __builtin_amdgcn_mfma_f32_16x16x32_bf16(
                        af[it], bf[ft], acc[it][ft], 0, 0, 0);
        }
        __syncthreads();
    }

    if (c_mode) {
        #pragma unroll
        for (int ft = 0; ft < 4; ++ft) {
            const int col = col0 + wc * 64 + ft * 16 + l15;
            const float bv = bias ? bias[col] : 0.f;
            #pragma unroll
            for (int it = 0; it < 4; ++it) {
                const int rbase = row0 + wr * 64 + it * 16 + quad * 4;
                #pragma unroll
                for (int rr = 0; rr < 4; ++rr) {
                    float v = acc[it][ft][rr] + bv;
                    if (relu) v = fmaxf(v, 0.f);
                    if (c_mode == 2)
                        ((unsigned short*)Cp)[(size_t)(rbase + rr) * Nc + col] = f2bf(v);
                    else
                        ((float*)Cp)[(size_t)(rbase + rr) * Nc + col] = v;
                }
            }
        }
    }

    if (Tout) {
        const int bb = row0 >> 12;
        #pragma unroll
        for (int ft = 0; ft < 4; ++ft) {
            const int col = col0 + wc * 64 + ft * 16 + l15;
            #pragma unroll
            for (int it = 0; it < 4; ++it) {
                const int ibase = (row0 & (N_ - 1)) + wr * 64 + it * 16 + quad * 4;
                ushort4 o;
                o.x = f2bf(acc[it][ft][0]); o.y = f2bf(acc[it][ft][1]);
                o.z = f2bf(acc[it][ft][2]); o.w = f2bf(acc[it][ft][3]);
                *(ushort4*)&Tout[((size_t)bb * F_ + col) * N_ + ibase] = o;
            }
        }
    }

    if (wha) {
        float a1v[4], a2v[4];
        #pragma unroll
        for (int ft = 0; ft < 4; ++ft) {
            const int col = col0 + wc * 64 + ft * 16 + l15;
            a1v[ft] = wha[col];
            a2v[ft] = wha[F_ + col];
        }
        #pragma unroll
        for (int it = 0; it < 4; ++it)
            #pragma unroll
            for (int rr = 0; rr < 4; ++rr) {
                float s1 = 0.f, s2 = 0.f;
                #pragma unroll
                for (int ft = 0; ft < 4; ++ft) {
                    s1 += acc[it][ft][rr] * a1v[ft];
                    s2 += acc[it][ft][rr] * a2v[ft];
                }
                #pragma unroll
                for (int mkk = 1; mkk < 16; mkk <<= 1) {
                    s1 += __shfl_xor(s1, mkk);
                    s2 += __shfl_xor(s2, mkk);
                }
                if (l15 == 0) {
                    const int row = row0 + wr * 64 + it * 16 + quad * 4 + rr;
                    atomicAdd(&Wh1[row], s1);
                    atomicAdd(&Wh2[row], s2);
                }
            }
    }
}

// ---------------- 64x128 bf16 MFMA GEMM (256 blocks -> full CU coverage) -------
__global__ __launch_bounds__(256) void gemm64_kernel(
    const void* __restrict__ Ap, const unsigned short* __restrict__ Wt,
    const float* __restrict__ bias, void* __restrict__ Cp,
    unsigned short* __restrict__ Tout, const float* __restrict__ wha,
    float* __restrict__ Wh1, float* __restrict__ Wh2,
    int Nc, int K, int relu, int a_bf16, int c_mode)
{
    __shared__ unsigned short As[64 * 72];
    __shared__ unsigned short Bs[128 * 72];
    const int t = threadIdx.x;
    const int w = t >> 6, l = t & 63;
    const int quad = l >> 4, l15 = l & 15;
    const int row0 = blockIdx.y * 64, col0 = blockIdx.x * 128;
    const int sra = t >> 2;            // 0..63
    const int ska = (t & 3) * 16;      // 0,16,32,48
    const int srb = t >> 1;            // 0..127
    const int skb = (t & 1) * 32;      // 0 or 32

    f32x4 acc[4][2];
    #pragma unroll
    for (int it = 0; it < 4; ++it)
        #pragma unroll
        for (int ft = 0; ft < 2; ++ft) acc[it][ft] = (f32x4)(0.f);

    for (int k0 = 0; k0 < K; k0 += 64) {
        if (a_bf16) {
            const unsigned short* ap =
                (const unsigned short*)Ap + (size_t)(row0 + sra) * K + k0 + ska;
            *(s16x8*)&As[sra * 72 + ska]     = *(const s16x8*)ap;
            *(s16x8*)&As[sra * 72 + ska + 8] = *(const s16x8*)(ap + 8);
        } else {
            const float* ap = (const float*)Ap + (size_t)(row0 + sra) * K + k0 + ska;
            #pragma unroll
            for (int u = 0; u < 4; ++u) {
                const float4 v = *(const float4*)(ap + u * 4);
                ushort4 o;
                o.x = f2bf(v.x); o.y = f2bf(v.y); o.z = f2bf(v.z); o.w = f2bf(v.w);
                *(ushort4*)&As[sra * 72 + ska + u * 4] = o;
            }
        }
        {
            const unsigned short* bp = Wt + (size_t)(col0 + srb) * K + k0 + skb;
            #pragma unroll
            for (int u = 0; u < 4; ++u)
                *(s16x8*)&Bs[srb * 72 + skb + u * 8] = *(const s16x8*)(bp + u * 8);
        }
        __syncthreads();
        #pragma unroll
        for (int ks = 0; ks < 64; ks += 32) {
            s16x8 af[4], bf[2];
            #pragma unroll
            for (int it = 0; it < 4; ++it)
                af[it] = *(const s16x8*)&As[(it * 16 + l15) * 72 + ks + quad * 8];
            #pragma unroll
            for (int ft = 0; ft < 2; ++ft)
                bf[ft] = *(const s16x8*)&Bs[(w * 32 + ft * 16 + l15) * 72 + ks + quad * 8];
            #pragma unroll
            for (int ft = 0; ft < 2; ++ft)
                #pragma unroll
                for (int it = 0; it < 4; ++it)
                    acc[it][ft] = __builtin_amdgcn_mfma_f32_16x16x32_bf16(
                        af[it], bf[ft], acc[it][ft], 0, 0, 0);
        }
        __syncthreads();
    }

    if (c_mode) {
        #pragma unroll
        for (int ft = 0; ft < 2; ++ft) {
            const int col = col0 + w * 32 + ft * 16 + l15;
            const float bv = bias ? bias[col] : 0.f;
            #pragma unroll
            for (int it = 0; it < 4; ++it) {
                const int rbase = row0 + it * 16 + quad * 4;
                #pragma unroll
                for (int rr = 0; rr < 4; ++rr) {
                    float v = acc[it][ft][rr] + bv;
                    if (relu) v = fmaxf(v, 0.f);
                    if (c_mode == 2)
                        ((unsigned short*)Cp)[(size_t)(rbase + rr) * Nc + col] = f2bf(v);
                    else
                        ((float*)Cp)[(size_t)(rbase + rr) * Nc + col] = v;
                }
            }
        }
    }

    if (Tout) {
        const int bb = row0 >> 12;
        #pragma unroll
        for (int ft = 0; ft < 2; ++ft) {
            const int col = col0 + w * 32 + ft * 16 + l15;
            #pragma unroll
            for (int it = 0; it < 4; ++it) {
                const int ibase = (row0 & (N_ - 1)) + it * 16 + quad * 4;
                ushort4 o;
                o.x = f2bf(acc[it][ft][0]); o.y = f2bf(acc[it][ft][1]);
                o.z = f2bf(acc[it][ft][2]); o.w = f2bf(acc[it][ft][3]);
                *(ushort4*)&Tout[((size_t)bb * F_ + col) * N_ + ibase] = o;
            }
        }
    }

    if (wha) {
        float a1v[2], a2v[2];
        #pragma unroll
        for (int ft = 0; ft < 2; ++ft) {
            const int col = col0 + w * 32 + ft * 16 + l15;
            a1v[ft] = wha[col];
            a2v[ft] = wha[F_ + col];
        }
        #pragma unroll
        for (int it = 0; it < 4; ++it)
            #pragma unroll
            for (int rr = 0; rr < 4; ++rr) {
                float s1 = acc[it][0][rr] * a1v[0] + acc[it][1][rr] * a1v[1];
                float s2 = acc[it][0][rr] * a2v[0] + acc[it][1][rr] * a2v[1];
                #pragma unroll
                for (int mkk = 1; mkk < 16; mkk <<= 1) {
                    s1 += __shfl_xor(s1, mkk);
                    s2 += __shfl_xor(s2, mkk);
                }
                if (l15 == 0) {
                    const int row = row0 + it * 16 + quad * 4 + rr;
                    atomicAdd(&Wh1[row], s1);
                    atomicAdd(&Wh2[row], s2);
                }
            }
    }
}

// ---------------- layer-1: adj -> stats + bitmask (fused, 8-wide ILP) ----------
__global__ __launch_bounds__(256) void colstats_adj_kernel(
    const int* __restrict__ adj, unsigned long long* __restrict__ maskOut,
    const float* __restrict__ Wh1, const float* __restrict__ Wh2,
    float* __restrict__ pM, float* __restrict__ pS)
{
    const int t = threadIdx.x;
    const int j = blockIdx.x * 256 + t;
    const int sp = blockIdx.y;
    const int b = blockIdx.z;
    const int i0 = sp * (N_ / SPLIT_);
    const int w = t >> 6, l = t & 63;
    const float w2 = Wh2[b * N_ + j];
    const float* __restrict__ w1p = Wh1 + b * N_ + i0;
    const int* __restrict__ ap = adj + ((size_t)b * N_ + i0) * N_ + j;

    float m = -3.4e38f, s = 0.f;
    for (int c = 0; c < N_ / SPLIT_; c += 8) {
        int v[8];
        #pragma unroll
        for (int u = 0; u < 8; ++u) v[u] = ap[(size_t)(c + u) * N_];
        float x[8];
        #pragma unroll
        for (int u = 0; u < 8; ++u) {
            const bool act = v[u] > 0;
            const unsigned long long bm = __ballot(act);
            if (l == 0)
                maskOut[((size_t)b * N_ + i0 + c + u) * (N_ / 64) + blockIdx.x * 4 + w] = bm;
            const float e0 = w1p[c + u] + w2;
            const float e = fmaxf(e0, ALPHA * e0);
            x[u] = act ? e : NEGV;
        }
        const float cm = fmaxf(fmaxf(fmaxf(x[0], x[1]), fmaxf(x[2], x[3])),
                               fmaxf(fmaxf(x[4], x[5]), fmaxf(x[6], x[7])));
        const float nm = fmaxf(m, cm);
        float cs = 0.f;
        #pragma unroll
        for (int u = 0; u < 8; ++u) cs += __expf(x[u] - nm);
        s = s * __expf(m - nm) + cs;
        m = nm;
    }
    pM[((size_t)b * SPLIT_ + sp) * N_ + j] = m;
    pS[((size_t)b * SPLIT_ + sp) * N_ + j] = s;
}

// ---------------- layer-2: stats from bitmask ----------------------------------
__global__ __launch_bounds__(256) void colstats3_kernel(
    const unsigned long long* __restrict__ mask,
    const float* __restrict__ Wh1, const float* __restrict__ Wh2,
    float* __restrict__ pM, float* __restrict__ pS)
{
    const int t = threadIdx.x;
    const int j = blockIdx.x * 256 + t;
    const int sp = blockIdx.y;
    const int b = blockIdx.z;
    const int i0 = sp * (N_ / SPLIT_);
    const int w = t >> 6;
    const int jbit = t & 63;
    const float w2 = Wh2[b * N_ + j];
    const unsigned long long* __restrict__ mbase =
        mask + ((size_t)b * N_ + i0) * (N_ / 64) + blockIdx.x * 4 + w;
    const float* __restrict__ w1p = Wh1 + b * N_ + i0;

    float m = -3.4e38f, s = 0.f;
    for (int c = 0; c < N_ / SPLIT_; c += 8) {
        float x[8];
        #pragma unroll
        for (int u = 0; u < 8; ++u) {
            const unsigned long long mw = mbase[(size_t)(c + u) * (N_ / 64)];
            const float e0 = w1p[c + u] + w2;
            const float e = fmaxf(e0, ALPHA * e0);
            x[u] = ((mw >> jbit) & 1ull) ? e : NEGV;
        }
        const float cm = fmaxf(fmaxf(fmaxf(x[0], x[1]), fmaxf(x[2], x[3])),
                               fmaxf(fmaxf(x[4], x[5]), fmaxf(x[6], x[7])));
        const float nm = fmaxf(m, cm);
        float cs = 0.f;
        #pragma unroll
        for (int u = 0; u < 8; ++u) cs += __expf(x[u] - nm);
        s = s * __expf(m - nm) + cs;
        m = nm;
    }
    pM[((size_t)b * SPLIT_ + sp) * N_ + j] = m;
    pS[((size_t)b * SPLIT_ + sp) * N_ + j] = s;
}

// ---------------- finalize: mo = m + ln(sum) -----------------------------------
__global__ __launch_bounds__(256) void colfin2_kernel(
    const float* __restrict__ pM, const float* __restrict__ pS,
    float* __restrict__ Mo)
{
    const int j = blockIdx.x * 256 + threadIdx.x;
    const int b = blockIdx.y;
    float m = -3.4e38f;
    #pragma unroll
    for (int s = 0; s < SPLIT_; ++s)
        m = fmaxf(m, pM[((size_t)b * SPLIT_ + s) * N_ + j]);
    float sum = 0.f;
    #pragma unroll
    for (int s = 0; s < SPLIT_; ++s)
        sum += pS[((size_t)b * SPLIT_ + s) * N_ + j] *
               __expf(pM[((size_t)b * SPLIT_ + s) * N_ + j] - m);
    Mo[b * N_ + j] = m + logf(sum);
}

// ---------------- attention v6: col-half split, 512 blocks, mask in LDS --------
// Grid 512 x 512 thr (8 waves). Block = 32 rows x 128 cols x full j-sweep.
// 2 blocks/CU (LDS 58.9KB) -> barrier drains of one block hidden by the other.
// computeP has ZERO global loads (mask/w2/mo staged in LDS); only global op is
// the B-fragment prefetch, consumed one phase later. Direct output (no partials).
// Bijective remap: xcd=lin&7 -> (b, colhalf) so each XCD L2 holds 1MB of Wht.
__global__ __launch_bounds__(512) void att_mfma6_kernel(
    const unsigned short* __restrict__ mask16, const unsigned short* __restrict__ Wht,
    const float* __restrict__ Wh1, const float* __restrict__ Wh2,
    const float* __restrict__ Mo, unsigned short* __restrict__ outb,
    float* __restrict__ outf)
{
    __shared__ unsigned short Ps[2][32 * 72];
    __shared__ float w2s[N_];
    __shared__ float mos[N_];
    __shared__ unsigned short msk[32 * 264];   // padded stride vs 256

    const int t = threadIdx.x;
    const int w = t >> 6, l = t & 63;
    const int quad = l >> 4, l15 = l & 15;

    const int lin = blockIdx.x;                // 0..511
    const int xcd = lin & 7;
    const int b = xcd >> 2;
    const int half = (xcd >> 1) & 1;
    const int tile = (lin >> 3) * 2 + (xcd & 1);   // 0..127
    const int i0 = tile * 32;
    const int c0 = half * 128;

    const int pi = t >> 4;      // P row 0..31
    const int pj4 = t & 15;     // j-quad within 64-step
    const float w1i = Wh1[b * N_ + i0 + pi];
    const unsigned short* __restrict__ WhtB = Wht + (size_t)b * F_ * N_;

    f32x4 acc[2];
    acc[0] = (f32x4)(0.f);
    acc[1] = (f32x4)(0.f);

    // wave w owns output col c0 + w*16 + l15
    const unsigned short* __restrict__ bbase =
        WhtB + (size_t)(c0 + w * 16 + l15) * N_ + quad * 8;

    s16x8 bA[2], bB[2];

    auto prefB = [&](int itr2, s16x8* dst) {
        const unsigned short* nb = bbase + itr2 * 64;
        dst[0] = *(const s16x8*)&nb[0];
        dst[1] = *(const s16x8*)&nb[32];
    };

    auto computeP = [&](int itr2, unsigned short* psdst) {
        const unsigned mb = msk[pi * 264 + itr2 * 4 + (pj4 >> 2)];
        const int bsh = (pj4 & 3) * 4;
        const int jl = itr2 * 64 + pj4 * 4;
        const float4 w2v = *(const float4*)&w2s[jl];
        const float4 mov = *(const float4*)&mos[jl];
        ushort4 o;
        unsigned short* op = &o.x;
        #pragma unroll
        for (int u = 0; u < 4; ++u) {
            const float xw = w1i + (&w2v.x)[u];
            const float e = fmaxf(xw, ALPHA * xw);
            const float x2 = ((mb >> (bsh + u)) & 1u) ? e : NEGV;
            op[u] = f2bf(__expf(x2 - (&mov.x)[u]));
        }
        *(ushort4*)&psdst[pi * 72 + pj4 * 4] = o;
    };

    auto mfmaStep = [&](const unsigned short* ps, const s16x8* breg) {
        #pragma unroll
        for (int ks = 0; ks < 2; ++ks) {
            #pragma unroll
            for (int it = 0; it < 2; ++it) {
                const s16x8 af =
                    *(const s16x8*)&ps[(it * 16 + l15) * 72 + ks * 32 + quad * 8];
                acc[it] = __builtin_amdgcn_mfma_f32_16x16x32_bf16(
                    af, breg[ks], acc[it], 0, 0, 0);
            }
        }
    };

    // prologue: issue first B prefetch, stage w2/mo/mask into LDS
    prefB(0, bA);
    #pragma unroll
    for (int k2 = 0; k2 < 2; ++k2) {
        const int i4 = t + k2 * 512;          // 0..1023
        *(float4*)&w2s[i4 * 4] = *(const float4*)&Wh2[b * N_ + i4 * 4];
        *(float4*)&mos[i4 * 4] = *(const float4*)&Mo[b * N_ + i4 * 4];
        const int mr = i4 >> 5, mc = i4 & 31; // 32 rows x 32 chunks of 8 ushorts
        *(s16x8*)&msk[mr * 264 + mc * 8] =
            *(const s16x8*)&mask16[(size_t)(b * N_ + i0 + mr) * 256 + mc * 8];
    }
    __syncthreads();            // staging ready
    computeP(0, &Ps[0][0]);
    __syncthreads();            // Ps[0] ready

    constexpr int NITER = N_ / 64;   // 64 (even)
    for (int itr = 0; itr < NITER; itr += 2) {
        prefB(itr + 1, bB);
        computeP(itr + 1, &Ps[1][0]);
        mfmaStep(&Ps[0][0], bA);
        __syncthreads();
        if (itr + 2 < NITER) {
            prefB(itr + 2, bA);
            computeP(itr + 2, &Ps[0][0]);
        }
        mfmaStep(&Ps[1][0], bB);
        __syncthreads();
    }

    const int col = c0 + w * 16 + l15;
    if (outb) {
        unsigned short* __restrict__ ob = outb + (size_t)(b * N_ + i0) * F_ + col;
        #pragma unroll
        for (int it = 0; it < 2; ++it)
            #pragma unroll
            for (int rr = 0; rr < 4; ++rr)
                ob[(size_t)(it * 16 + quad * 4 + rr) * F_] = f2bf(acc[it][rr]);
    } else {
        float* __restrict__ of = outf + (size_t)(b * N_ + i0) * F_ + col;
        #pragma unroll
        for (int it = 0; it < 2; ++it)
            #pragma unroll
            for (int rr = 0; rr < 4; ++rr)
                of[(size_t)(it * 16 + quad * 4 + rr) * F_] = acc[it][rr];
    }
}

// ---------------- x + attout + LayerNorm -> fp32 + bf16 ------------------------
__global__ __launch_bounds__(256) void addln2b_kernel(
    const float* __restrict__ X, const float* __restrict__ Y,
    const float* __restrict__ g, const float* __restrict__ bta,
    float* __restrict__ outf, unsigned short* __restrict__ outb)
{
    const int row = blockIdx.x;
    const int t = threadIdx.x;
    const size_t idx = (size_t)row * F_ + t;
    const float v = X[idx] + Y[idx];
    float s1 = v, s2 = v * v;
    #pragma unroll
    for (int off = 32; off > 0; off >>= 1) {
        s1 += __shfl_down(s1, off);
        s2 += __shfl_down(s2, off);
    }
    __shared__ float r1[4], r2[4];
    __shared__ float mu_s, rs_s;
    const int wid = t >> 6, lane = t & 63;
    if (lane == 0) { r1[wid] = s1; r2[wid] = s2; }
    __syncthreads();
    if (t == 0) {
        const float a = r1[0] + r1[1] + r1[2] + r1[3];
        const float q = r2[0] + r2[1] + r2[2] + r2[3];
        const float mu = a * (1.f / F_);
        const float var = q * (1.f / F_) - mu * mu;
        mu_s = mu;
        rs_s = rsqrtf(var + EPSV);
    }
    __syncthreads();
    const float r = (v - mu_s) * rs_s * g[t] + bta[t];
    outf[idx] = r;
    outb[idx] = f2bf(r);
}

// ---------------- residual add + LayerNorm (final) -----------------------------
__global__ __launch_bounds__(256) void addln_kernel(
    const float* __restrict__ X, const float* __restrict__ Y,
    const float* __restrict__ g, const float* __restrict__ bta,
    float* __restrict__ out)
{
    const int row = blockIdx.x;
    const int t = threadIdx.x;
    const size_t idx = (size_t)row * F_ + t;
    const float v = X[idx] + Y[idx];
    float s1 = v, s2 = v * v;
    #pragma unroll
    for (int off = 32; off > 0; off >>= 1) {
        s1 += __shfl_down(s1, off);
        s2 += __shfl_down(s2, off);
    }
    __shared__ float r1[4], r2[4];
    __shared__ float mu_s, rs_s;
    const int wid = t >> 6, lane = t & 63;
    if (lane == 0) { r1[wid] = s1; r2[wid] = s2; }
    __syncthreads();
    if (t == 0) {
        const float a = r1[0] + r1[1] + r1[2] + r1[3];
        const float q = r2[0] + r2[1] + r2[2] + r2[3];
        const float mu = a * (1.f / F_);
        const float var = q * (1.f / F_) - mu * mu;
        mu_s = mu;
        rs_s = rsqrtf(var + EPSV);
    }
    __syncthreads();
    out[idx] = (v - mu_s) * rs_s * g[t] + bta[t];
}

// -------------------------------------------------------------------------------
extern "C" void kernel_launch(void* const* d_in, const int* in_sizes, int n_in,
                              void* d_out, int out_size, void* d_ws, size_t ws_size,
                              hipStream_t stream)
{
    const float* x     = (const float*)d_in[0];
    const int*   adj   = (const int*)d_in[1];
    const float* W1    = (const float*)d_in[2];
    const float* a1    = (const float*)d_in[3];
    const float* W2    = (const float*)d_in[4];
    const float* a2    = (const float*)d_in[5];
    const float* w_ff1 = (const float*)d_in[6];
    const float* b_ff1 = (const float*)d_in[7];
    const float* w_ff2 = (const float*)d_in[8];
    const float* b_ff2 = (const float*)d_in[9];
    const float* g_ln1 = (const float*)d_in[10];
    const float* b_ln1 = (const float*)d_in[11];
    const float* g_ln2 = (const float*)d_in[12];
    const float* b_ln2 = (const float*)d_in[13];
    float* out = (float*)d_out;

    const int Rtot = B_ * N_;             // 8192
    char* wsb = (char*)d_ws;
    float* attout = (float*)wsb;                                 // 8 MB
    float* ln1   = (float*)(wsb + 33554432);                     // 8 MB
    float* ffout = (float*)(wsb + 41943040);                     // 8 MB
    unsigned short* mid  = (unsigned short*)(wsb + 50331648);    // 16 MB
    unsigned short* ln1b = (unsigned short*)(wsb + 67108864);    // 4 MB
    unsigned short* g1b  = (unsigned short*)(wsb + 71303168);    // 4 MB
    unsigned short* Wht  = (unsigned short*)(wsb + 75497472);    // 4 MB
    unsigned long long* mask = (unsigned long long*)(wsb + 79691776); // 4 MB
    unsigned short* mask16 = (unsigned short*)mask;
    unsigned short* Wt1  = (unsigned short*)(wsb + 83886080);    // 128 KB
    unsigned short* Wt2  = Wt1 + 65536;                          // 128 KB
    unsigned short* Wtf1 = Wt2 + 65536;                          // 512 KB
    unsigned short* Wtf2 = Wtf1 + 262144;                        // 512 KB
    float* WhA1 = (float*)(wsb + 85196800);
    float* WhA2 = WhA1 + 8192;
    float* WhB1 = WhA2 + 8192;
    float* WhB2 = WhB1 + 8192;
    float* Mo   = (float*)(wsb + 85327872);                      // 32 KB
    float* pM   = (float*)(wsb + 85360640);                      // 512 KB
    float* pS   = (float*)(wsb + 85884928);                      // 512 KB

    const dim3 statsG(N_ / 256, SPLIT_, B_);
    const dim3 finG(N_ / 256, B_);

    // ===== prologue: zero atomic targets, transpose all weights =====
    zero_kernel<<<32, 256, 0, stream>>>(WhA1);   // covers WhA1..WhB2 (32768 f)
    transp_all_kernel<<<dim3(16, 16, 4), 256, 0, stream>>>(
        W1, W2, w_ff1, w_ff2, Wt1, Wt2, Wtf1, Wtf2);

    // ===== GAT layer 1 =====
    gemm64_kernel<<<dim3(2, 128), 256, 0, stream>>>(
        x, Wt1, nullptr, nullptr, Wht, a1, WhA1, WhA2, F_, F_, 0, 0, 0);
    colstats_adj_kernel<<<statsG, 256, 0, stream>>>(adj, mask, WhA1, WhA2, pM, pS);
    colfin2_kernel<<<finG, 256, 0, stream>>>(pM, pS, Mo);
    att_mfma6_kernel<<<512, 512, 0, stream>>>(
        mask16, Wht, WhA1, WhA2, Mo, g1b, nullptr);

    // ===== GAT layer 2 (mask reused) =====
    gemm64_kernel<<<dim3(2, 128), 256, 0, stream>>>(
        g1b, Wt2, nullptr, nullptr, Wht, a2, WhB1, WhB2, F_, F_, 0, 1, 0);
    colstats3_kernel<<<statsG, 256, 0, stream>>>(mask, WhB1, WhB2, pM, pS);
    colfin2_kernel<<<finG, 256, 0, stream>>>(pM, pS, Mo);
    att_mfma6_kernel<<<512, 512, 0, stream>>>(
        mask16, Wht, WhB1, WhB2, Mo, nullptr, attout);

    // ===== LN1(x + attout) -> ln1 fp32 + ln1b bf16 =====
    addln2b_kernel<<<Rtot, 256, 0, stream>>>(x, attout, g_ln1, b_ln1, ln1, ln1b);

    // ===== FFN =====
    gemm128_kernel<<<dim3(8, 64), 256, 0, stream>>>(
        ln1b, Wtf1, b_ff1, mid, nullptr, nullptr, nullptr, nullptr, H_, F_, 1, 1, 2);
    gemm64_kernel<<<dim3(2, 128), 256, 0, stream>>>(
        mid, Wtf2, b_ff2, ffout, nullptr, nullptr, nullptr, nullptr, F_, H_, 0, 1, 1);

    // ===== LN2(ln1 + ff) =====
    addln_kernel<<<Rtot, 256, 0, stream>>>(ln1, ffout, g_ln2, b_ln2, out);
}

// Round 4
// 425.797 us; speedup vs baseline: 1.1393x; 1.0623x over previous
//
#include <hip/hip_runtime.h>
#include <math.h>

#define ALPHA 0.2f
#define NEGV  -9e15f
#define EPSV  1e-5f

constexpr int B_ = 2, N_ = 4096, F_ = 256, H_ = 1024;
constexpr int SPLIT_ = 16;   // colstats i-split
constexpr int SPLITJ_ = 4;   // attention j-split

typedef __attribute__((ext_vector_type(4))) float f32x4;
typedef __attribute__((ext_vector_type(8))) short s16x8;

__device__ __forceinline__ unsigned short f2bf(float f) {
    unsigned u = __builtin_bit_cast(unsigned, f);
    u += 0x7fffu + ((u >> 16) & 1u);
    return (unsigned short)(u >> 16);
}

// ---------------- batched weight transpose + bf16 (+ fused zero of Wh scratch) -
// src[R][C] -> dst[C][R]; idle blocks (z==0, y>=4) zero the 32768-float Wh area.
__global__ __launch_bounds__(256) void transp_all_kernel(
    const float* __restrict__ W1, const float* __restrict__ W2,
    const float* __restrict__ F1s, const float* __restrict__ F2s,
    unsigned short* __restrict__ D1, unsigned short* __restrict__ D2,
    unsigned short* __restrict__ D3, unsigned short* __restrict__ D4,
    float* __restrict__ Zp)
{
    const int mi = blockIdx.z;
    const float* src; unsigned short* dst; int R, Cc;
    if (mi == 0)      { src = W1;  dst = D1; R = 256;  Cc = 256; }
    else if (mi == 1) { src = W2;  dst = D2; R = 256;  Cc = 256; }
    else if (mi == 2) { src = F1s; dst = D3; R = 256;  Cc = 1024; }
    else              { src = F2s; dst = D4; R = 1024; Cc = 256; }
    const int r0 = blockIdx.x * 64, c0 = blockIdx.y * 64;
    const int t = threadIdx.x;

    if (mi == 0 && blockIdx.y >= 4) {
        // fused zero: 32 blocks cover 32768 floats (WhA1..WhB2)
        const int lid = (blockIdx.y - 4) * 16 + blockIdx.x;   // 0..191
        if (lid < 32) {
            const int i = (lid * 256 + t) * 4;
            *(float4*)&Zp[i] = make_float4(0.f, 0.f, 0.f, 0.f);
        }
        return;
    }
    if (r0 >= R || c0 >= Cc) return;

    __shared__ float T[64][65];
    #pragma unroll
    for (int s = 0; s < 4; ++s) {
        const int rr = s * 16 + (t >> 4);
        const int cq = t & 15;
        const float4 v = *(const float4*)&src[(size_t)(r0 + rr) * Cc + c0 + cq * 4];
        T[rr][cq * 4 + 0] = v.x; T[rr][cq * 4 + 1] = v.y;
        T[rr][cq * 4 + 2] = v.z; T[rr][cq * 4 + 3] = v.w;
    }
    __syncthreads();
    #pragma unroll
    for (int s = 0; s < 4; ++s) {
        const int cr = s * 16 + (t >> 4);
        const int rq = t & 15;
        ushort4 o;
        o.x = f2bf(T[rq * 4 + 0][cr]);
        o.y = f2bf(T[rq * 4 + 1][cr]);
        o.z = f2bf(T[rq * 4 + 2][cr]);
        o.w = f2bf(T[rq * 4 + 3][cr]);
        *(ushort4*)&dst[(size_t)(c0 + cr) * R + r0 + rq * 4] = o;
    }
}

// ---------------- 128x128 bf16 MFMA GEMM (used for FFN1: 512 blocks) -----------
__global__ __launch_bounds__(256) void gemm128_kernel(
    const void* __restrict__ Ap, const unsigned short* __restrict__ Wt,
    const float* __restrict__ bias, void* __restrict__ Cp,
    unsigned short* __restrict__ Tout, const float* __restrict__ wha,
    float* __restrict__ Wh1, float* __restrict__ Wh2,
    int Nc, int K, int relu, int a_bf16, int c_mode)
{
    __shared__ unsigned short As[128 * 72];
    __shared__ unsigned short Bs[128 * 72];
    const int t = threadIdx.x;
    const int w = t >> 6, l = t & 63;
    const int quad = l >> 4, l15 = l & 15;
    const int wr = w & 1, wc = w >> 1;
    const int row0 = blockIdx.y * 128, col0 = blockIdx.x * 128;
    const int sr = t >> 1;           // 0..127
    const int sk = (t & 1) * 32;     // 0 or 32

    f32x4 acc[4][4];
    #pragma unroll
    for (int it = 0; it < 4; ++it)
        #pragma unroll
        for (int ft = 0; ft < 4; ++ft) acc[it][ft] = (f32x4)(0.f);

    for (int k0 = 0; k0 < K; k0 += 64) {
        if (a_bf16) {
            const unsigned short* ap =
                (const unsigned short*)Ap + (size_t)(row0 + sr) * K + k0 + sk;
            #pragma unroll
            for (int u = 0; u < 4; ++u)
                *(s16x8*)&As[sr * 72 + sk + u * 8] = *(const s16x8*)(ap + u * 8);
        } else {
            const float* ap = (const float*)Ap + (size_t)(row0 + sr) * K + k0 + sk;
            #pragma unroll
            for (int u = 0; u < 8; ++u) {
                const float4 v = *(const float4*)(ap + u * 4);
                ushort4 o;
                o.x = f2bf(v.x); o.y = f2bf(v.y); o.z = f2bf(v.z); o.w = f2bf(v.w);
                *(ushort4*)&As[sr * 72 + sk + u * 4] = o;
            }
        }
        {
            const unsigned short* bp = Wt + (size_t)(col0 + sr) * K + k0 + sk;
            #pragma unroll
            for (int u = 0; u < 4; ++u)
                *(s16x8*)&Bs[sr * 72 + sk + u * 8] = *(const s16x8*)(bp + u * 8);
        }
        __syncthreads();
        #pragma unroll
        for (int ks = 0; ks < 64; ks += 32) {
            s16x8 af[4], bf[4];
            #pragma unroll
            for (int it = 0; it < 4; ++it)
                af[it] = *(const s16x8*)&As[(wr * 64 + it * 16 + l15) * 72 + ks + quad * 8];
            #pragma unroll
            for (int ft = 0; ft < 4; ++ft)
                bf[ft] = *(const s16x8*)&Bs[(wc * 64 + ft * 16 + l15) * 72 + ks + quad * 8];
            #pragma unroll
            for (int ft = 0; ft < 4; ++ft)
                #pragma unroll
                for (int it = 0; it < 4; ++it)
                    acc[it][ft] = __builtin_amdgcn_mfma_f32_16x16x32_bf16(
                        af[it], bf[ft], acc[it][ft], 0, 0, 0);
        }
        __syncthreads();
    }

    if (c_mode) {
        #pragma unroll
        for (int ft = 0; ft < 4; ++ft) {
            const int col = col0 + wc * 64 + ft * 16 + l15;
            const float bv = bias ? bias[col] : 0.f;
            #pragma unroll
            for (int it = 0; it < 4; ++it) {
                const int rbase = row0 + wr * 64 + it * 16 + quad * 4;
                #pragma unroll
                for (int rr = 0; rr < 4; ++rr) {
                    float v = acc[it][ft][rr] + bv;
                    if (relu) v = fmaxf(v, 0.f);
                    if (c_mode == 2)
                        ((unsigned short*)Cp)[(size_t)(rbase + rr) * Nc + col] = f2bf(v);
                    else
                        ((float*)Cp)[(size_t)(rbase + rr) * Nc + col] = v;
                }
            }
        }
    }

    if (Tout) {
        const int bb = row0 >> 12;
        #pragma unroll
        for (int ft = 0; ft < 4; ++ft) {
            const int col = col0 + wc * 64 + ft * 16 + l15;
            #pragma unroll
            for (int it = 0; it < 4; ++it) {
                const int ibase = (row0 & (N_ - 1)) + wr * 64 + it * 16 + quad * 4;
                ushort4 o;
                o.x = f2bf(acc[it][ft][0]); o.y = f2bf(acc[it][ft][1]);
                o.z = f2bf(acc[it][ft][2]); o.w = f2bf(acc[it][ft][3]);
                *(ushort4*)&Tout[((size_t)bb * F_ + col) * N_ + ibase] = o;
            }
        }
    }

    if (wha) {
        float a1v[4], a2v[4];
        #pragma unroll
        for (int ft = 0; ft < 4; ++ft) {
            const int col = col0 + wc * 64 + ft * 16 + l15;
            a1v[ft] = wha[col];
            a2v[ft] = wha[F_ + col];
        }
        #pragma unroll
        for (int it = 0; it < 4; ++it)
            #pragma unroll
            for (int rr = 0; rr < 4; ++rr) {
                float s1 = 0.f, s2 = 0.f;
                #pragma unroll
                for (int ft = 0; ft < 4; ++ft) {
                    s1 += acc[it][ft][rr] * a1v[ft];
                    s2 += acc[it][ft][rr] * a2v[ft];
                }
                #pragma unroll
                for (int mkk = 1; mkk < 16; mkk <<= 1) {
                    s1 += __shfl_xor(s1, mkk);
                    s2 += __shfl_xor(s2, mkk);
                }
                if (l15 == 0) {
                    const int row = row0 + wr * 64 + it * 16 + quad * 4 + rr;
                    atomicAdd(&Wh1[row], s1);
                    atomicAdd(&Wh2[row], s2);
                }
            }
    }
}

// ---------------- 64x128 bf16 MFMA GEMM (256 blocks) ---------------------------
// a_mode: 0 fp32, 1 bf16, 2 = A is sum of 4 fp32 partials (stride S), summed
// in reduce4b's exact order then f2bf -> bit-identical to the old reduce4b path.
__global__ __launch_bounds__(256) void gemm64_kernel(
    const void* __restrict__ Ap, const unsigned short* __restrict__ Wt,
    const float* __restrict__ bias, void* __restrict__ Cp,
    unsigned short* __restrict__ Tout, const float* __restrict__ wha,
    float* __restrict__ Wh1, float* __restrict__ Wh2,
    int Nc, int K, int relu, int a_mode, int c_mode)
{
    __shared__ unsigned short As[64 * 72];
    __shared__ unsigned short Bs[128 * 72];
    const int t = threadIdx.x;
    const int w = t >> 6, l = t & 63;
    const int quad = l >> 4, l15 = l & 15;
    const int row0 = blockIdx.y * 64, col0 = blockIdx.x * 128;
    const int sra = t >> 2;            // 0..63
    const int ska = (t & 3) * 16;      // 0,16,32,48
    const int srb = t >> 1;            // 0..127
    const int skb = (t & 1) * 32;      // 0 or 32

    f32x4 acc[4][2];
    #pragma unroll
    for (int it = 0; it < 4; ++it)
        #pragma unroll
        for (int ft = 0; ft < 2; ++ft) acc[it][ft] = (f32x4)(0.f);

    for (int k0 = 0; k0 < K; k0 += 64) {
        if (a_mode == 1) {
            const unsigned short* ap =
                (const unsigned short*)Ap + (size_t)(row0 + sra) * K + k0 + ska;
            *(s16x8*)&As[sra * 72 + ska]     = *(const s16x8*)ap;
            *(s16x8*)&As[sra * 72 + ska + 8] = *(const s16x8*)(ap + 8);
        } else if (a_mode == 0) {
            const float* ap = (const float*)Ap + (size_t)(row0 + sra) * K + k0 + ska;
            #pragma unroll
            for (int u = 0; u < 4; ++u) {
                const float4 v = *(const float4*)(ap + u * 4);
                ushort4 o;
                o.x = f2bf(v.x); o.y = f2bf(v.y); o.z = f2bf(v.z); o.w = f2bf(v.w);
                *(ushort4*)&As[sra * 72 + ska + u * 4] = o;
            }
        } else {
            const size_t S = (size_t)B_ * N_ * F_;
            const float* ap = (const float*)Ap + (size_t)(row0 + sra) * K + k0 + ska;
            #pragma unroll
            for (int u = 0; u < 4; ++u) {
                const float4 a = *(const float4*)(ap + u * 4);
                const float4 b = *(const float4*)(ap + S + u * 4);
                const float4 c = *(const float4*)(ap + 2 * S + u * 4);
                const float4 d = *(const float4*)(ap + 3 * S + u * 4);
                ushort4 o;
                o.x = f2bf(a.x + b.x + c.x + d.x);
                o.y = f2bf(a.y + b.y + c.y + d.y);
                o.z = f2bf(a.z + b.z + c.z + d.z);
                o.w = f2bf(a.w + b.w + c.w + d.w);
                *(ushort4*)&As[sra * 72 + ska + u * 4] = o;
            }
        }
        {
            const unsigned short* bp = Wt + (size_t)(col0 + srb) * K + k0 + skb;
            #pragma unroll
            for (int u = 0; u < 4; ++u)
                *(s16x8*)&Bs[srb * 72 + skb + u * 8] = *(const s16x8*)(bp + u * 8);
        }
        __syncthreads();
        #pragma unroll
        for (int ks = 0; ks < 64; ks += 32) {
            s16x8 af[4], bf[2];
            #pragma unroll
            for (int it = 0; it < 4; ++it)
                af[it] = *(const s16x8*)&As[(it * 16 + l15) * 72 + ks + quad * 8];
            #pragma unroll
            for (int ft = 0; ft < 2; ++ft)
                bf[ft] = *(const s16x8*)&Bs[(w * 32 + ft * 16 + l15) * 72 + ks + quad * 8];
            #pragma unroll
            for (int ft = 0; ft < 2; ++ft)
                #pragma unroll
                for (int it = 0; it < 4; ++it)
                    acc[it][ft] = __builtin_amdgcn_mfma_f32_16x16x32_bf16(
                        af[it], bf[ft], acc[it][ft], 0, 0, 0);
        }
        __syncthreads();
    }

    if (c_mode) {
        #pragma unroll
        for (int ft = 0; ft < 2; ++ft) {
            const int col = col0 + w * 32 + ft * 16 + l15;
            const float bv = bias ? bias[col] : 0.f;
            #pragma unroll
            for (int it = 0; it < 4; ++it) {
                const int rbase = row0 + it * 16 + quad * 4;
                #pragma unroll
                for (int rr = 0; rr < 4; ++rr) {
                    float v = acc[it][ft][rr] + bv;
                    if (relu) v = fmaxf(v, 0.f);
                    if (c_mode == 2)
                        ((unsigned short*)Cp)[(size_t)(rbase + rr) * Nc + col] = f2bf(v);
                    else
                        ((float*)Cp)[(size_t)(rbase + rr) * Nc + col] = v;
                }
            }
        }
    }

    if (Tout) {
        const int bb = row0 >> 12;
        #pragma unroll
        for (int ft = 0; ft < 2; ++ft) {
            const int col = col0 + w * 32 + ft * 16 + l15;
            #pragma unroll
            for (int it = 0; it < 4; ++it) {
                const int ibase = (row0 & (N_ - 1)) + it * 16 + quad * 4;
                ushort4 o;
                o.x = f2bf(acc[it][ft][0]); o.y = f2bf(acc[it][ft][1]);
                o.z = f2bf(acc[it][ft][2]); o.w = f2bf(acc[it][ft][3]);
                *(ushort4*)&Tout[((size_t)bb * F_ + col) * N_ + ibase] = o;
            }
        }
    }

    if (wha) {
        float a1v[2], a2v[2];
        #pragma unroll
        for (int ft = 0; ft < 2; ++ft) {
            const int col = col0 + w * 32 + ft * 16 + l15;
            a1v[ft] = wha[col];
            a2v[ft] = wha[F_ + col];
        }
        #pragma unroll
        for (int it = 0; it < 4; ++it)
            #pragma unroll
            for (int rr = 0; rr < 4; ++rr) {
                float s1 = acc[it][0][rr] * a1v[0] + acc[it][1][rr] * a1v[1];
                float s2 = acc[it][0][rr] * a2v[0] + acc[it][1][rr] * a2v[1];
                #pragma unroll
                for (int mkk = 1; mkk < 16; mkk <<= 1) {
                    s1 += __shfl_xor(s1, mkk);
                    s2 += __shfl_xor(s2, mkk);
                }
                if (l15 == 0) {
                    const int row = row0 + it * 16 + quad * 4 + rr;
                    atomicAdd(&Wh1[row], s1);
                    atomicAdd(&Wh2[row], s2);
                }
            }
    }
}

// ---------------- layer-1: adj -> stats + bitmask (fused, 8-wide ILP) ----------
__global__ __launch_bounds__(256) void colstats_adj_kernel(
    const int* __restrict__ adj, unsigned long long* __restrict__ maskOut,
    const float* __restrict__ Wh1, const float* __restrict__ Wh2,
    float* __restrict__ pM, float* __restrict__ pS)
{
    const int t = threadIdx.x;
    const int j = blockIdx.x * 256 + t;
    const int sp = blockIdx.y;
    const int b = blockIdx.z;
    const int i0 = sp * (N_ / SPLIT_);
    const int w = t >> 6, l = t & 63;
    const float w2 = Wh2[b * N_ + j];
    const float* __restrict__ w1p = Wh1 + b * N_ + i0;
    const int* __restrict__ ap = adj + ((size_t)b * N_ + i0) * N_ + j;

    float m = -3.4e38f, s = 0.f;
    for (int c = 0; c < N_ / SPLIT_; c += 8) {
        int v[8];
        #pragma unroll
        for (int u = 0; u < 8; ++u) v[u] = ap[(size_t)(c + u) * N_];
        float x[8];
        #pragma unroll
        for (int u = 0; u < 8; ++u) {
            const bool act = v[u] > 0;
            const unsigned long long bm = __ballot(act);
            if (l == 0)
                maskOut[((size_t)b * N_ + i0 + c + u) * (N_ / 64) + blockIdx.x * 4 + w] = bm;
            const float e0 = w1p[c + u] + w2;
            const float e = fmaxf(e0, ALPHA * e0);
            x[u] = act ? e : NEGV;
        }
        const float cm = fmaxf(fmaxf(fmaxf(x[0], x[1]), fmaxf(x[2], x[3])),
                               fmaxf(fmaxf(x[4], x[5]), fmaxf(x[6], x[7])));
        const float nm = fmaxf(m, cm);
        float cs = 0.f;
        #pragma unroll
        for (int u = 0; u < 8; ++u) cs += __expf(x[u] - nm);
        s = s * __expf(m - nm) + cs;
        m = nm;
    }
    pM[((size_t)b * SPLIT_ + sp) * N_ + j] = m;
    pS[((size_t)b * SPLIT_ + sp) * N_ + j] = s;
}

// ---------------- layer-2: stats from bitmask ----------------------------------
__global__ __launch_bounds__(256) void colstats3_kernel(
    const unsigned long long* __restrict__ mask,
    const float* __restrict__ Wh1, const float* __restrict__ Wh2,
    float* __restrict__ pM, float* __restrict__ pS)
{
    const int t = threadIdx.x;
    const int j = blockIdx.x * 256 + t;
    const int sp = blockIdx.y;
    const int b = blockIdx.z;
    const int i0 = sp * (N_ / SPLIT_);
    const int w = t >> 6;
    const int jbit = t & 63;
    const float w2 = Wh2[b * N_ + j];
    const unsigned long long* __restrict__ mbase =
        mask + ((size_t)b * N_ + i0) * (N_ / 64) + blockIdx.x * 4 + w;
    const float* __restrict__ w1p = Wh1 + b * N_ + i0;

    float m = -3.4e38f, s = 0.f;
    for (int c = 0; c < N_ / SPLIT_; c += 8) {
        float x[8];
        #pragma unroll
        for (int u = 0; u < 8; ++u) {
            const unsigned long long mw = mbase[(size_t)(c + u) * (N_ / 64)];
            const float e0 = w1p[c + u] + w2;
            const float e = fmaxf(e0, ALPHA * e0);
            x[u] = ((mw >> jbit) & 1ull) ? e : NEGV;
        }
        const float cm = fmaxf(fmaxf(fmaxf(x[0], x[1]), fmaxf(x[2], x[3])),
                               fmaxf(fmaxf(x[4], x[5]), fmaxf(x[6], x[7])));
        const float nm = fmaxf(m, cm);
        float cs = 0.f;
        #pragma unroll
        for (int u = 0; u < 8; ++u) cs += __expf(x[u] - nm);
        s = s * __expf(m - nm) + cs;
        m = nm;
    }
    pM[((size_t)b * SPLIT_ + sp) * N_ + j] = m;
    pS[((size_t)b * SPLIT_ + sp) * N_ + j] = s;
}

// ---------------- finalize: mo = m + ln(sum) -----------------------------------
__global__ __launch_bounds__(256) void colfin2_kernel(
    const float* __restrict__ pM, const float* __restrict__ pS,
    float* __restrict__ Mo)
{
    const int j = blockIdx.x * 256 + threadIdx.x;
    const int b = blockIdx.y;
    float m = -3.4e38f;
    #pragma unroll
    for (int s = 0; s < SPLIT_; ++s)
        m = fmaxf(m, pM[((size_t)b * SPLIT_ + s) * N_ + j]);
    float sum = 0.f;
    #pragma unroll
    for (int s = 0; s < SPLIT_; ++s)
        sum += pS[((size_t)b * SPLIT_ + s) * N_ + j] *
               __expf(pM[((size_t)b * SPLIT_ + s) * N_ + j] - m);
    Mo[b * N_ + j] = m + logf(sum);
}

// ---------------- attention matmul v4 (proven r1): direct-global B, P dbuf -----
__global__ __launch_bounds__(256, 2) void att_mfma4_kernel(
    const unsigned short* __restrict__ mask16, const unsigned short* __restrict__ Wht,
    const float* __restrict__ Wh1, const float* __restrict__ Wh2,
    const float* __restrict__ Mo, float* __restrict__ part)
{
    __shared__ unsigned short Ps[2][64 * 72];
    __shared__ float w2s[1024];
    __shared__ float mos[1024];

    const int t = threadIdx.x;
    const int w = t >> 6, l = t & 63;
    const int quad = l >> 4, l15 = l & 15;

    const int lin = blockIdx.x + (blockIdx.y << 6) + (blockIdx.z << 8);
    const int xcd = lin & 7;
    const int b = xcd >> 2;
    const int sp = xcd & 3;
    const int i0 = (lin >> 3) << 6;
    const int jbase = sp * (N_ / SPLITJ_);

    const int pi = t >> 2;
    const int pj4 = t & 3;
    const float w1i = Wh1[b * N_ + i0 + pi];
    const unsigned short* __restrict__ mrow =
        mask16 + ((size_t)b * N_ + i0 + pi) * (N_ / 16) + pj4;
    const unsigned short* __restrict__ WhtB = Wht + (size_t)b * F_ * N_;

    {
        const float4 a = *(const float4*)&Wh2[b * N_ + jbase + t * 4];
        const float4 c = *(const float4*)&Mo[b * N_ + jbase + t * 4];
        *(float4*)&w2s[t * 4] = a;
        *(float4*)&mos[t * 4] = c;
    }

    f32x4 acc[4][4];
    #pragma unroll
    for (int it = 0; it < 4; ++it)
        #pragma unroll
        for (int ft = 0; ft < 4; ++ft) acc[it][ft] = (f32x4)(0.f);

    const unsigned short* __restrict__ bbase =
        WhtB + (size_t)(w * 64 + l15) * N_ + jbase + quad * 8;

    s16x8 bA[8], bB[8];

    auto prefB = [&](int itr2, s16x8* dst) {
        const unsigned short* nb = bbase + itr2 * 64;
        #pragma unroll
        for (int ft = 0; ft < 4; ++ft)
            #pragma unroll
            for (int kk = 0; kk < 2; ++kk)
                dst[ft * 2 + kk] = *(const s16x8*)&nb[(size_t)ft * 16 * N_ + kk * 32];
    };

    auto computeP = [&](int itr2, unsigned short* psdst) {
        const int jl = itr2 * 64 + pj4 * 16;
        const unsigned mb = mrow[(jbase >> 4) + itr2 * 4];
        s16x8 o0, o1;
        #pragma unroll
        for (int u4 = 0; u4 < 4; ++u4) {
            const float4 w2v = *(const float4*)&w2s[jl + u4 * 4];
            const float4 mov = *(const float4*)&mos[jl + u4 * 4];
            #pragma unroll
            for (int u = 0; u < 4; ++u) {
                const float xw = w1i + (&w2v.x)[u];
                const float e = fmaxf(xw, ALPHA * xw);
                const float x2 = ((mb >> (u4 * 4 + u)) & 1u) ? e : NEGV;
                const short pv = (short)f2bf(__expf(x2 - (&mov.x)[u]));
                if (u4 < 2) o0[u4 * 4 + u] = pv;
                else        o1[(u4 - 2) * 4 + u] = pv;
            }
        }
        *(s16x8*)&psdst[pi * 72 + pj4 * 16]     = o0;
        *(s16x8*)&psdst[pi * 72 + pj4 * 16 + 8] = o1;
    };

    auto mfmaStep = [&](const unsigned short* ps, const s16x8* breg) {
        #pragma unroll
        for (int ksidx = 0; ksidx < 2; ++ksidx) {
            s16x8 af[4];
            #pragma unroll
            for (int it = 0; it < 4; ++it)
                af[it] = *(const s16x8*)&ps[(it * 16 + l15) * 72 + ksidx * 32 + quad * 8];
            #pragma unroll
            for (int ft = 0; ft < 4; ++ft)
                #pragma unroll
                for (int it = 0; it < 4; ++it)
                    acc[it][ft] = __builtin_amdgcn_mfma_f32_16x16x32_bf16(
                        af[it], breg[ft * 2 + ksidx], acc[it][ft], 0, 0, 0);
        }
    };

    prefB(0, bA);
    __syncthreads();
    computeP(0, &Ps[0][0]);
    __syncthreads();

    constexpr int NITER = (N_ / SPLITJ_) / 64;   // 16
    for (int itr = 0; itr < NITER; itr += 2) {
        prefB(itr + 1, bB);
        computeP(itr + 1, &Ps[1][0]);
        mfmaStep(&Ps[0][0], bA);
        __syncthreads();
        if (itr + 2 < NITER) {
            prefB(itr + 2, bA);
            computeP(itr + 2, &Ps[0][0]);
        }
        mfmaStep(&Ps[1][0], bB);
        __syncthreads();
    }

    float* __restrict__ pout = part + ((size_t)sp * B_ + b) * N_ * F_;
    #pragma unroll
    for (int it = 0; it < 4; ++it)
        #pragma unroll
        for (int ft = 0; ft < 4; ++ft) {
            const int col = w * 64 + ft * 16 + l15;
            #pragma unroll
            for (int rr = 0; rr < 4; ++rr) {
                const int row = i0 + it * 16 + quad * 4 + rr;
                pout[(size_t)row * F_ + col] = acc[it][ft][rr];
            }
        }
}

// ---------------- x + 4-way partial sum + LayerNorm -> fp32 + bf16 -------------
__global__ __launch_bounds__(256) void addln4_kernel(
    const float* __restrict__ X, const float* __restrict__ p,
    const float* __restrict__ g, const float* __restrict__ bta,
    float* __restrict__ outf, unsigned short* __restrict__ outb)
{
    const int row = blockIdx.x;
    const int t = threadIdx.x;
    const size_t idx = (size_t)row * F_ + t;
    const size_t S = (size_t)B_ * N_ * F_;
    const float v = X[idx] + p[idx] + p[idx + S] + p[idx + 2 * S] + p[idx + 3 * S];
    float s1 = v, s2 = v * v;
    #pragma unroll
    for (int off = 32; off > 0; off >>= 1) {
        s1 += __shfl_down(s1, off);
        s2 += __shfl_down(s2, off);
    }
    __shared__ float r1[4], r2[4];
    __shared__ float mu_s, rs_s;
    const int wid = t >> 6, lane = t & 63;
    if (lane == 0) { r1[wid] = s1; r2[wid] = s2; }
    __syncthreads();
    if (t == 0) {
        const float a = r1[0] + r1[1] + r1[2] + r1[3];
        const float q = r2[0] + r2[1] + r2[2] + r2[3];
        const float mu = a * (1.f / F_);
        const float var = q * (1.f / F_) - mu * mu;
        mu_s = mu;
        rs_s = rsqrtf(var + EPSV);
    }
    __syncthreads();
    const float r = (v - mu_s) * rs_s * g[t] + bta[t];
    outf[idx] = r;
    outb[idx] = f2bf(r);
}

// ---------------- residual add + LayerNorm (final) -----------------------------
__global__ __launch_bounds__(256) void addln_kernel(
    const float* __restrict__ X, const float* __restrict__ Y,
    const float* __restrict__ g, const float* __restrict__ bta,
    float* __restrict__ out)
{
    const int row = blockIdx.x;
    const int t = threadIdx.x;
    const size_t idx = (size_t)row * F_ + t;
    const float v = X[idx] + Y[idx];
    float s1 = v, s2 = v * v;
    #pragma unroll
    for (int off = 32; off > 0; off >>= 1) {
        s1 += __shfl_down(s1, off);
        s2 += __shfl_down(s2, off);
    }
    __shared__ float r1[4], r2[4];
    __shared__ float mu_s, rs_s;
    const int wid = t >> 6, lane = t & 63;
    if (lane == 0) { r1[wid] = s1; r2[wid] = s2; }
    __syncthreads();
    if (t == 0) {
        const float a = r1[0] + r1[1] + r1[2] + r1[3];
        const float q = r2[0] + r2[1] + r2[2] + r2[3];
        const float mu = a * (1.f / F_);
        const float var = q * (1.f / F_) - mu * mu;
        mu_s = mu;
        rs_s = rsqrtf(var + EPSV);
    }
    __syncthreads();
    out[idx] = (v - mu_s) * rs_s * g[t] + bta[t];
}

// -------------------------------------------------------------------------------
extern "C" void kernel_launch(void* const* d_in, const int* in_sizes, int n_in,
                              void* d_out, int out_size, void* d_ws, size_t ws_size,
                              hipStream_t stream)
{
    const float* x     = (const float*)d_in[0];
    const int*   adj   = (const int*)d_in[1];
    const float* W1    = (const float*)d_in[2];
    const float* a1    = (const float*)d_in[3];
    const float* W2    = (const float*)d_in[4];
    const float* a2    = (const float*)d_in[5];
    const float* w_ff1 = (const float*)d_in[6];
    const float* b_ff1 = (const float*)d_in[7];
    const float* w_ff2 = (const float*)d_in[8];
    const float* b_ff2 = (const float*)d_in[9];
    const float* g_ln1 = (const float*)d_in[10];
    const float* b_ln1 = (const float*)d_in[11];
    const float* g_ln2 = (const float*)d_in[12];
    const float* b_ln2 = (const float*)d_in[13];
    float* out = (float*)d_out;

    const int Rtot = B_ * N_;             // 8192
    char* wsb = (char*)d_ws;
    float* part  = (float*)wsb;                                  // 32 MB
    float* ln1   = (float*)(wsb + 33554432);                     // 8 MB
    float* ffout = (float*)(wsb + 41943040);                     // 8 MB
    unsigned short* mid  = (unsigned short*)(wsb + 50331648);    // 16 MB
    unsigned short* ln1b = (unsigned short*)(wsb + 67108864);    // 4 MB
    unsigned short* Wht  = (unsigned short*)(wsb + 75497472);    // 4 MB
    unsigned long long* mask = (unsigned long long*)(wsb + 79691776); // 4 MB
    unsigned short* mask16 = (unsigned short*)mask;
    unsigned short* Wt1  = (unsigned short*)(wsb + 83886080);    // 128 KB
    unsigned short* Wt2  = Wt1 + 65536;                          // 128 KB
    unsigned short* Wtf1 = Wt2 + 65536;                          // 512 KB
    unsigned short* Wtf2 = Wtf1 + 262144;                        // 512 KB
    float* WhA1 = (float*)(wsb + 85196800);
    float* WhA2 = WhA1 + 8192;
    float* WhB1 = WhA2 + 8192;
    float* WhB2 = WhB1 + 8192;
    float* Mo   = (float*)(wsb + 85327872);                      // 32 KB
    float* pM   = (float*)(wsb + 85360640);                      // 512 KB
    float* pS   = (float*)(wsb + 85884928);                      // 512 KB

    const dim3 statsG(N_ / 256, SPLIT_, B_);
    const dim3 finG(N_ / 256, B_);
    const dim3 attG(N_ / 64, SPLITJ_, B_);

    // ===== prologue: transpose weights + fused zero of Wh scratch =====
    transp_all_kernel<<<dim3(16, 16, 4), 256, 0, stream>>>(
        W1, W2, w_ff1, w_ff2, Wt1, Wt2, Wtf1, Wtf2, WhA1);

    // ===== GAT layer 1 =====
    gemm64_kernel<<<dim3(2, 128), 256, 0, stream>>>(
        x, Wt1, nullptr, nullptr, Wht, a1, WhA1, WhA2, F_, F_, 0, 0, 0);
    colstats_adj_kernel<<<statsG, 256, 0, stream>>>(adj, mask, WhA1, WhA2, pM, pS);
    colfin2_kernel<<<finG, 256, 0, stream>>>(pM, pS, Mo);
    att_mfma4_kernel<<<attG, 256, 0, stream>>>(mask16, Wht, WhA1, WhA2, Mo, part);

    // ===== GAT layer 2: A = sum of 4 partials, fused in GEMM (mask reused) =====
    gemm64_kernel<<<dim3(2, 128), 256, 0, stream>>>(
        part, Wt2, nullptr, nullptr, Wht, a2, WhB1, WhB2, F_, F_, 0, 2, 0);
    colstats3_kernel<<<statsG, 256, 0, stream>>>(mask, WhB1, WhB2, pM, pS);
    colfin2_kernel<<<finG, 256, 0, stream>>>(pM, pS, Mo);
    att_mfma4_kernel<<<attG, 256, 0, stream>>>(mask16, Wht, WhB1, WhB2, Mo, part);

    // ===== LN1(x + sum of 4 att partials) -> ln1 fp32 + ln1b bf16 =====
    addln4_kernel<<<Rtot, 256, 0, stream>>>(x, part, g_ln1, b_ln1, ln1, ln1b);

    // ===== FFN =====
    gemm128_kernel<<<dim3(8, 64), 256, 0, stream>>>(
        ln1b, Wtf1, b_ff1, mid, nullptr, nullptr, nullptr, nullptr, H_, F_, 1, 1, 2);
    gemm64_kernel<<<dim3(2, 128), 256, 0, stream>>>(
        mid, Wtf2, b_ff2, ffout, nullptr, nullptr, nullptr, nullptr, F_, H_, 0, 1, 1);

    // ===== LN2(ln1 + ff) =====
    addln_kernel<<<Rtot, 256, 0, stream>>>(ln1, ffout, g_ln2, b_ln2, out);
}

// Round 5
// 418.305 us; speedup vs baseline: 1.1597x; 1.0179x over previous
//
#include <hip/hip_runtime.h>
#include <math.h>

#define ALPHA 0.2f
#define NEGV  -9e15f
#define EPSV  1e-5f

constexpr int B_ = 2, N_ = 4096, F_ = 256, H_ = 1024;
constexpr int SPLIT_ = 16;   // colstats i-split
constexpr int SPLITJ_ = 4;   // attention j-split

typedef __attribute__((ext_vector_type(4))) float f32x4;
typedef __attribute__((ext_vector_type(8))) short s16x8;

__device__ __forceinline__ unsigned short f2bf(float f) {
    unsigned u = __builtin_bit_cast(unsigned, f);
    u += 0x7fffu + ((u >> 16) & 1u);
    return (unsigned short)(u >> 16);
}

// ---------------- batched weight transpose + bf16 (+ fused zero of Wh scratch) -
__global__ __launch_bounds__(256) void transp_all_kernel(
    const float* __restrict__ W1, const float* __restrict__ W2,
    const float* __restrict__ F1s, const float* __restrict__ F2s,
    unsigned short* __restrict__ D1, unsigned short* __restrict__ D2,
    unsigned short* __restrict__ D3, unsigned short* __restrict__ D4,
    float* __restrict__ Zp)
{
    const int mi = blockIdx.z;
    const float* src; unsigned short* dst; int R, Cc;
    if (mi == 0)      { src = W1;  dst = D1; R = 256;  Cc = 256; }
    else if (mi == 1) { src = W2;  dst = D2; R = 256;  Cc = 256; }
    else if (mi == 2) { src = F1s; dst = D3; R = 256;  Cc = 1024; }
    else              { src = F2s; dst = D4; R = 1024; Cc = 256; }
    const int r0 = blockIdx.x * 64, c0 = blockIdx.y * 64;
    const int t = threadIdx.x;

    if (mi == 0 && blockIdx.y >= 4) {
        const int lid = (blockIdx.y - 4) * 16 + blockIdx.x;   // 0..191
        if (lid < 32) {
            const int i = (lid * 256 + t) * 4;
            *(float4*)&Zp[i] = make_float4(0.f, 0.f, 0.f, 0.f);
        }
        return;
    }
    if (r0 >= R || c0 >= Cc) return;

    __shared__ float T[64][65];
    #pragma unroll
    for (int s = 0; s < 4; ++s) {
        const int rr = s * 16 + (t >> 4);
        const int cq = t & 15;
        const float4 v = *(const float4*)&src[(size_t)(r0 + rr) * Cc + c0 + cq * 4];
        T[rr][cq * 4 + 0] = v.x; T[rr][cq * 4 + 1] = v.y;
        T[rr][cq * 4 + 2] = v.z; T[rr][cq * 4 + 3] = v.w;
    }
    __syncthreads();
    #pragma unroll
    for (int s = 0; s < 4; ++s) {
        const int cr = s * 16 + (t >> 4);
        const int rq = t & 15;
        ushort4 o;
        o.x = f2bf(T[rq * 4 + 0][cr]);
        o.y = f2bf(T[rq * 4 + 1][cr]);
        o.z = f2bf(T[rq * 4 + 2][cr]);
        o.w = f2bf(T[rq * 4 + 3][cr]);
        *(ushort4*)&dst[(size_t)(c0 + cr) * R + r0 + rq * 4] = o;
    }
}

// ---------------- 128x128 bf16 MFMA GEMM (used for FFN1: 512 blocks) -----------
__global__ __launch_bounds__(256) void gemm128_kernel(
    const void* __restrict__ Ap, const unsigned short* __restrict__ Wt,
    const float* __restrict__ bias, void* __restrict__ Cp,
    unsigned short* __restrict__ Tout, const float* __restrict__ wha,
    float* __restrict__ Wh1, float* __restrict__ Wh2,
    int Nc, int K, int relu, int a_bf16, int c_mode)
{
    __shared__ unsigned short As[128 * 72];
    __shared__ unsigned short Bs[128 * 72];
    const int t = threadIdx.x;
    const int w = t >> 6, l = t & 63;
    const int quad = l >> 4, l15 = l & 15;
    const int wr = w & 1, wc = w >> 1;
    const int row0 = blockIdx.y * 128, col0 = blockIdx.x * 128;
    const int sr = t >> 1;           // 0..127
    const int sk = (t & 1) * 32;     // 0 or 32

    f32x4 acc[4][4];
    #pragma unroll
    for (int it = 0; it < 4; ++it)
        #pragma unroll
        for (int ft = 0; ft < 4; ++ft) acc[it][ft] = (f32x4)(0.f);

    for (int k0 = 0; k0 < K; k0 += 64) {
        if (a_bf16) {
            const unsigned short* ap =
                (const unsigned short*)Ap + (size_t)(row0 + sr) * K + k0 + sk;
            #pragma unroll
            for (int u = 0; u < 4; ++u)
                *(s16x8*)&As[sr * 72 + sk + u * 8] = *(const s16x8*)(ap + u * 8);
        } else {
            const float* ap = (const float*)Ap + (size_t)(row0 + sr) * K + k0 + sk;
            #pragma unroll
            for (int u = 0; u < 8; ++u) {
                const float4 v = *(const float4*)(ap + u * 4);
                ushort4 o;
                o.x = f2bf(v.x); o.y = f2bf(v.y); o.z = f2bf(v.z); o.w = f2bf(v.w);
                *(ushort4*)&As[sr * 72 + sk + u * 4] = o;
            }
        }
        {
            const unsigned short* bp = Wt + (size_t)(col0 + sr) * K + k0 + sk;
            #pragma unroll
            for (int u = 0; u < 4; ++u)
                *(s16x8*)&Bs[sr * 72 + sk + u * 8] = *(const s16x8*)(bp + u * 8);
        }
        __syncthreads();
        #pragma unroll
        for (int ks = 0; ks < 64; ks += 32) {
            s16x8 af[4], bf[4];
            #pragma unroll
            for (int it = 0; it < 4; ++it)
                af[it] = *(const s16x8*)&As[(wr * 64 + it * 16 + l15) * 72 + ks + quad * 8];
            #pragma unroll
            for (int ft = 0; ft < 4; ++ft)
                bf[ft] = *(const s16x8*)&Bs[(wc * 64 + ft * 16 + l15) * 72 + ks + quad * 8];
            #pragma unroll
            for (int ft = 0; ft < 4; ++ft)
                #pragma unroll
                for (int it = 0; it < 4; ++it)
                    acc[it][ft] = __builtin_amdgcn_mfma_f32_16x16x32_bf16(
                        af[it], bf[ft], acc[it][ft], 0, 0, 0);
        }
        __syncthreads();
    }

    if (c_mode) {
        #pragma unroll
        for (int ft = 0; ft < 4; ++ft) {
            const int col = col0 + wc * 64 + ft * 16 + l15;
            const float bv = bias ? bias[col] : 0.f;
            #pragma unroll
            for (int it = 0; it < 4; ++it) {
                const int rbase = row0 + wr * 64 + it * 16 + quad * 4;
                #pragma unroll
                for (int rr = 0; rr < 4; ++rr) {
                    float v = acc[it][ft][rr] + bv;
                    if (relu) v = fmaxf(v, 0.f);
                    if (c_mode == 2)
                        ((unsigned short*)Cp)[(size_t)(rbase + rr) * Nc + col] = f2bf(v);
                    else
                        ((float*)Cp)[(size_t)(rbase + rr) * Nc + col] = v;
                }
            }
        }
    }

    if (Tout) {
        const int bb = row0 >> 12;
        #pragma unroll
        for (int ft = 0; ft < 4; ++ft) {
            const int col = col0 + wc * 64 + ft * 16 + l15;
            #pragma unroll
            for (int it = 0; it < 4; ++it) {
                const int ibase = (row0 & (N_ - 1)) + wr * 64 + it * 16 + quad * 4;
                ushort4 o;
                o.x = f2bf(acc[it][ft][0]); o.y = f2bf(acc[it][ft][1]);
                o.z = f2bf(acc[it][ft][2]); o.w = f2bf(acc[it][ft][3]);
                *(ushort4*)&Tout[((size_t)bb * F_ + col) * N_ + ibase] = o;
            }
        }
    }

    if (wha) {
        float a1v[4], a2v[4];
        #pragma unroll
        for (int ft = 0; ft < 4; ++ft) {
            const int col = col0 + wc * 64 + ft * 16 + l15;
            a1v[ft] = wha[col];
            a2v[ft] = wha[F_ + col];
        }
        #pragma unroll
        for (int it = 0; it < 4; ++it)
            #pragma unroll
            for (int rr = 0; rr < 4; ++rr) {
                float s1 = 0.f, s2 = 0.f;
                #pragma unroll
                for (int ft = 0; ft < 4; ++ft) {
                    s1 += acc[it][ft][rr] * a1v[ft];
                    s2 += acc[it][ft][rr] * a2v[ft];
                }
                #pragma unroll
                for (int mkk = 1; mkk < 16; mkk <<= 1) {
                    s1 += __shfl_xor(s1, mkk);
                    s2 += __shfl_xor(s2, mkk);
                }
                if (l15 == 0) {
                    const int row = row0 + wr * 64 + it * 16 + quad * 4 + rr;
                    atomicAdd(&Wh1[row], s1);
                    atomicAdd(&Wh2[row], s2);
                }
            }
    }
}

// ---------------- 32x128 bf16 MFMA GEMM (512 blocks -> 2 blocks/CU) ------------
// a_mode: 0 fp32, 1 bf16, 2 = sum of 4 fp32 partial streams (reduce4b order).
__global__ __launch_bounds__(256) void gemm32_kernel(
    const void* __restrict__ Ap, const unsigned short* __restrict__ Wt,
    const float* __restrict__ bias, void* __restrict__ Cp,
    unsigned short* __restrict__ Tout, const float* __restrict__ wha,
    float* __restrict__ Wh1, float* __restrict__ Wh2,
    int Nc, int K, int relu, int a_mode, int c_mode)
{
    __shared__ unsigned short As[32 * 72];
    __shared__ unsigned short Bs[128 * 72];
    const int t = threadIdx.x;
    const int w = t >> 6, l = t & 63;
    const int quad = l >> 4, l15 = l & 15;
    const int row0 = blockIdx.y * 32, col0 = blockIdx.x * 128;
    const int sra = t >> 3;            // 0..31
    const int ska = (t & 7) * 8;       // 0..56
    const int srb = t >> 1;            // 0..127
    const int skb = (t & 1) * 32;      // 0 or 32

    f32x4 acc[2][2];
    #pragma unroll
    for (int it = 0; it < 2; ++it)
        #pragma unroll
        for (int ft = 0; ft < 2; ++ft) acc[it][ft] = (f32x4)(0.f);

    for (int k0 = 0; k0 < K; k0 += 64) {
        if (a_mode == 1) {
            const unsigned short* ap =
                (const unsigned short*)Ap + (size_t)(row0 + sra) * K + k0 + ska;
            *(s16x8*)&As[sra * 72 + ska] = *(const s16x8*)ap;
        } else if (a_mode == 0) {
            const float* ap = (const float*)Ap + (size_t)(row0 + sra) * K + k0 + ska;
            #pragma unroll
            for (int u = 0; u < 2; ++u) {
                const float4 v = *(const float4*)(ap + u * 4);
                ushort4 o;
                o.x = f2bf(v.x); o.y = f2bf(v.y); o.z = f2bf(v.z); o.w = f2bf(v.w);
                *(ushort4*)&As[sra * 72 + ska + u * 4] = o;
            }
        } else {
            const size_t S = (size_t)B_ * N_ * F_;
            const float* ap = (const float*)Ap + (size_t)(row0 + sra) * K + k0 + ska;
            #pragma unroll
            for (int u = 0; u < 2; ++u) {
                const float4 a = *(const float4*)(ap + u * 4);
                const float4 b = *(const float4*)(ap + S + u * 4);
                const float4 c = *(const float4*)(ap + 2 * S + u * 4);
                const float4 d = *(const float4*)(ap + 3 * S + u * 4);
                ushort4 o;
                o.x = f2bf(a.x + b.x + c.x + d.x);
                o.y = f2bf(a.y + b.y + c.y + d.y);
                o.z = f2bf(a.z + b.z + c.z + d.z);
                o.w = f2bf(a.w + b.w + c.w + d.w);
                *(ushort4*)&As[sra * 72 + ska + u * 4] = o;
            }
        }
        {
            const unsigned short* bp = Wt + (size_t)(col0 + srb) * K + k0 + skb;
            #pragma unroll
            for (int u = 0; u < 4; ++u)
                *(s16x8*)&Bs[srb * 72 + skb + u * 8] = *(const s16x8*)(bp + u * 8);
        }
        __syncthreads();
        #pragma unroll
        for (int ks = 0; ks < 64; ks += 32) {
            s16x8 af[2], bf[2];
            #pragma unroll
            for (int it = 0; it < 2; ++it)
                af[it] = *(const s16x8*)&As[(it * 16 + l15) * 72 + ks + quad * 8];
            #pragma unroll
            for (int ft = 0; ft < 2; ++ft)
                bf[ft] = *(const s16x8*)&Bs[(w * 32 + ft * 16 + l15) * 72 + ks + quad * 8];
            #pragma unroll
            for (int ft = 0; ft < 2; ++ft)
                #pragma unroll
                for (int it = 0; it < 2; ++it)
                    acc[it][ft] = __builtin_amdgcn_mfma_f32_16x16x32_bf16(
                        af[it], bf[ft], acc[it][ft], 0, 0, 0);
        }
        __syncthreads();
    }

    if (c_mode) {
        #pragma unroll
        for (int ft = 0; ft < 2; ++ft) {
            const int col = col0 + w * 32 + ft * 16 + l15;
            const float bv = bias ? bias[col] : 0.f;
            #pragma unroll
            for (int it = 0; it < 2; ++it) {
                const int rbase = row0 + it * 16 + quad * 4;
                #pragma unroll
                for (int rr = 0; rr < 4; ++rr) {
                    float v = acc[it][ft][rr] + bv;
                    if (relu) v = fmaxf(v, 0.f);
                    if (c_mode == 2)
                        ((unsigned short*)Cp)[(size_t)(rbase + rr) * Nc + col] = f2bf(v);
                    else
                        ((float*)Cp)[(size_t)(rbase + rr) * Nc + col] = v;
                }
            }
        }
    }

    if (Tout) {
        const int bb = row0 >> 12;
        #pragma unroll
        for (int ft = 0; ft < 2; ++ft) {
            const int col = col0 + w * 32 + ft * 16 + l15;
            #pragma unroll
            for (int it = 0; it < 2; ++it) {
                const int ibase = (row0 & (N_ - 1)) + it * 16 + quad * 4;
                ushort4 o;
                o.x = f2bf(acc[it][ft][0]); o.y = f2bf(acc[it][ft][1]);
                o.z = f2bf(acc[it][ft][2]); o.w = f2bf(acc[it][ft][3]);
                *(ushort4*)&Tout[((size_t)bb * F_ + col) * N_ + ibase] = o;
            }
        }
    }

    if (wha) {
        float a1v[2], a2v[2];
        #pragma unroll
        for (int ft = 0; ft < 2; ++ft) {
            const int col = col0 + w * 32 + ft * 16 + l15;
            a1v[ft] = wha[col];
            a2v[ft] = wha[F_ + col];
        }
        #pragma unroll
        for (int it = 0; it < 2; ++it)
            #pragma unroll
            for (int rr = 0; rr < 4; ++rr) {
                float s1 = acc[it][0][rr] * a1v[0] + acc[it][1][rr] * a1v[1];
                float s2 = acc[it][0][rr] * a2v[0] + acc[it][1][rr] * a2v[1];
                #pragma unroll
                for (int mkk = 1; mkk < 16; mkk <<= 1) {
                    s1 += __shfl_xor(s1, mkk);
                    s2 += __shfl_xor(s2, mkk);
                }
                if (l15 == 0) {
                    const int row = row0 + it * 16 + quad * 4 + rr;
                    atomicAdd(&Wh1[row], s1);
                    atomicAdd(&Wh2[row], s2);
                }
            }
    }
}

// ---------------- layer-1: adj -> stats + bitmask (fused, 8-wide ILP) ----------
__global__ __launch_bounds__(256) void colstats_adj_kernel(
    const int* __restrict__ adj, unsigned long long* __restrict__ maskOut,
    const float* __restrict__ Wh1, const float* __restrict__ Wh2,
    float* __restrict__ pM, float* __restrict__ pS)
{
    const int t = threadIdx.x;
    const int j = blockIdx.x * 256 + t;
    const int sp = blockIdx.y;
    const int b = blockIdx.z;
    const int i0 = sp * (N_ / SPLIT_);
    const int w = t >> 6, l = t & 63;
    const float w2 = Wh2[b * N_ + j];
    const float* __restrict__ w1p = Wh1 + b * N_ + i0;
    const int* __restrict__ ap = adj + ((size_t)b * N_ + i0) * N_ + j;

    float m = -3.4e38f, s = 0.f;
    for (int c = 0; c < N_ / SPLIT_; c += 8) {
        int v[8];
        #pragma unroll
        for (int u = 0; u < 8; ++u) v[u] = ap[(size_t)(c + u) * N_];
        float x[8];
        #pragma unroll
        for (int u = 0; u < 8; ++u) {
            const bool act = v[u] > 0;
            const unsigned long long bm = __ballot(act);
            if (l == 0)
                maskOut[((size_t)b * N_ + i0 + c + u) * (N_ / 64) + blockIdx.x * 4 + w] = bm;
            const float e0 = w1p[c + u] + w2;
            const float e = fmaxf(e0, ALPHA * e0);
            x[u] = act ? e : NEGV;
        }
        const float cm = fmaxf(fmaxf(fmaxf(x[0], x[1]), fmaxf(x[2], x[3])),
                               fmaxf(fmaxf(x[4], x[5]), fmaxf(x[6], x[7])));
        const float nm = fmaxf(m, cm);
        float cs = 0.f;
        #pragma unroll
        for (int u = 0; u < 8; ++u) cs += __expf(x[u] - nm);
        s = s * __expf(m - nm) + cs;
        m = nm;
    }
    pM[((size_t)b * SPLIT_ + sp) * N_ + j] = m;
    pS[((size_t)b * SPLIT_ + sp) * N_ + j] = s;
}

// ---------------- layer-2: stats from bitmask ----------------------------------
__global__ __launch_bounds__(256) void colstats3_kernel(
    const unsigned long long* __restrict__ mask,
    const float* __restrict__ Wh1, const float* __restrict__ Wh2,
    float* __restrict__ pM, float* __restrict__ pS)
{
    const int t = threadIdx.x;
    const int j = blockIdx.x * 256 + t;
    const int sp = blockIdx.y;
    const int b = blockIdx.z;
    const int i0 = sp * (N_ / SPLIT_);
    const int w = t >> 6;
    const int jbit = t & 63;
    const float w2 = Wh2[b * N_ + j];
    const unsigned long long* __restrict__ mbase =
        mask + ((size_t)b * N_ + i0) * (N_ / 64) + blockIdx.x * 4 + w;
    const float* __restrict__ w1p = Wh1 + b * N_ + i0;

    float m = -3.4e38f, s = 0.f;
    for (int c = 0; c < N_ / SPLIT_; c += 8) {
        float x[8];
        #pragma unroll
        for (int u = 0; u < 8; ++u) {
            const unsigned long long mw = mbase[(size_t)(c + u) * (N_ / 64)];
            const float e0 = w1p[c + u] + w2;
            const float e = fmaxf(e0, ALPHA * e0);
            x[u] = ((mw >> jbit) & 1ull) ? e : NEGV;
        }
        const float cm = fmaxf(fmaxf(fmaxf(x[0], x[1]), fmaxf(x[2], x[3])),
                               fmaxf(fmaxf(x[4], x[5]), fmaxf(x[6], x[7])));
        const float nm = fmaxf(m, cm);
        float cs = 0.f;
        #pragma unroll
        for (int u = 0; u < 8; ++u) cs += __expf(x[u] - nm);
        s = s * __expf(m - nm) + cs;
        m = nm;
    }
    pM[((size_t)b * SPLIT_ + sp) * N_ + j] = m;
    pS[((size_t)b * SPLIT_ + sp) * N_ + j] = s;
}

// ---------------- finalize: mo = m + ln(sum) -----------------------------------
__global__ __launch_bounds__(256) void colfin2_kernel(
    const float* __restrict__ pM, const float* __restrict__ pS,
    float* __restrict__ Mo)
{
    const int j = blockIdx.x * 256 + threadIdx.x;
    const int b = blockIdx.y;
    float m = -3.4e38f;
    #pragma unroll
    for (int s = 0; s < SPLIT_; ++s)
        m = fmaxf(m, pM[((size_t)b * SPLIT_ + s) * N_ + j]);
    float sum = 0.f;
    #pragma unroll
    for (int s = 0; s < SPLIT_; ++s)
        sum += pS[((size_t)b * SPLIT_ + s) * N_ + j] *
               __expf(pM[((size_t)b * SPLIT_ + s) * N_ + j] - m);
    Mo[b * N_ + j] = m + logf(sum);
}

// ---------------- attention v7: same tiles as v4, 8 waves -> 16 waves/CU -------
// Block = 64 i x 256 F x 1024 j, 512 threads. Wave w owns 32 F-cols ->
// acc[4][2]=32 + bA/bB 32 VGPR => fits 4 waves/SIMD (2 blocks x 8 waves = 50%).
// Same P values, same j/k accumulation order as v4 -> bit-identical output.
__global__ __launch_bounds__(512, 4) void att_mfma7_kernel(
    const unsigned short* __restrict__ mask16, const unsigned short* __restrict__ Wht,
    const float* __restrict__ Wh1, const float* __restrict__ Wh2,
    const float* __restrict__ Mo, float* __restrict__ part)
{
    __shared__ unsigned short Ps[2][64 * 72];
    __shared__ float w2s[1024];
    __shared__ float mos[1024];

    const int t = threadIdx.x;
    const int w = t >> 6, l = t & 63;
    const int quad = l >> 4, l15 = l & 15;

    const int lin = blockIdx.x + (blockIdx.y << 6) + (blockIdx.z << 8);
    const int xcd = lin & 7;
    const int b = xcd >> 2;
    const int sp = xcd & 3;
    const int i0 = (lin >> 3) << 6;
    const int jbase = sp * (N_ / SPLITJ_);

    const int pi = t >> 3;      // P row 0..63
    const int pj8 = t & 7;      // 8-j group within 64-step
    const float w1i = Wh1[b * N_ + i0 + pi];
    const unsigned short* __restrict__ mrow =
        mask16 + ((size_t)b * N_ + i0 + pi) * (N_ / 16);
    const unsigned short* __restrict__ WhtB = Wht + (size_t)b * F_ * N_;

    if (t < 256) {
        const float4 a = *(const float4*)&Wh2[b * N_ + jbase + t * 4];
        const float4 c = *(const float4*)&Mo[b * N_ + jbase + t * 4];
        *(float4*)&w2s[t * 4] = a;
        *(float4*)&mos[t * 4] = c;
    }

    f32x4 acc[4][2];
    #pragma unroll
    for (int it = 0; it < 4; ++it)
        #pragma unroll
        for (int ft = 0; ft < 2; ++ft) acc[it][ft] = (f32x4)(0.f);

    // wave w owns cols w*32 + ft*16 + l15 (ft 0..1)
    const unsigned short* __restrict__ bbase =
        WhtB + (size_t)(w * 32 + l15) * N_ + jbase + quad * 8;

    s16x8 bA[4], bB[4];

    auto prefB = [&](int itr2, s16x8* dst) {
        const unsigned short* nb = bbase + itr2 * 64;
        #pragma unroll
        for (int ft = 0; ft < 2; ++ft)
            #pragma unroll
            for (int kk = 0; kk < 2; ++kk)
                dst[ft * 2 + kk] = *(const s16x8*)&nb[(size_t)ft * 16 * N_ + kk * 32];
    };

    auto computeP = [&](int itr2, unsigned short* psdst) {
        const unsigned mword = mrow[(jbase >> 4) + itr2 * 4 + (pj8 >> 1)];
        const unsigned mb = (mword >> ((pj8 & 1) * 8)) & 0xffu;
        const int jl = itr2 * 64 + pj8 * 8;
        s16x8 o;
        #pragma unroll
        for (int u4 = 0; u4 < 2; ++u4) {
            const float4 w2v = *(const float4*)&w2s[jl + u4 * 4];
            const float4 mov = *(const float4*)&mos[jl + u4 * 4];
            #pragma unroll
            for (int u = 0; u < 4; ++u) {
                const float xw = w1i + (&w2v.x)[u];
                const float e = fmaxf(xw, ALPHA * xw);
                const float x2 = ((mb >> (u4 * 4 + u)) & 1u) ? e : NEGV;
                o[u4 * 4 + u] = (short)f2bf(__expf(x2 - (&mov.x)[u]));
            }
        }
        *(s16x8*)&psdst[pi * 72 + pj8 * 8] = o;
    };

    auto mfmaStep = [&](const unsigned short* ps, const s16x8* breg) {
        #pragma unroll
        for (int ksidx = 0; ksidx < 2; ++ksidx) {
            s16x8 af[4];
            #pragma unroll
            for (int it = 0; it < 4; ++it)
                af[it] = *(const s16x8*)&ps[(it * 16 + l15) * 72 + ksidx * 32 + quad * 8];
            #pragma unroll
            for (int ft = 0; ft < 2; ++ft)
                #pragma unroll
                for (int it = 0; it < 4; ++it)
                    acc[it][ft] = __builtin_amdgcn_mfma_f32_16x16x32_bf16(
                        af[it], breg[ft * 2 + ksidx], acc[it][ft], 0, 0, 0);
        }
    };

    prefB(0, bA);
    __syncthreads();
    computeP(0, &Ps[0][0]);
    __syncthreads();

    constexpr int NITER = (N_ / SPLITJ_) / 64;   // 16
    for (int itr = 0; itr < NITER; itr += 2) {
        prefB(itr + 1, bB);
        computeP(itr + 1, &Ps[1][0]);
        mfmaStep(&Ps[0][0], bA);
        __syncthreads();
        if (itr + 2 < NITER) {
            prefB(itr + 2, bA);
            computeP(itr + 2, &Ps[0][0]);
        }
        mfmaStep(&Ps[1][0], bB);
        __syncthreads();
    }

    float* __restrict__ pout = part + ((size_t)sp * B_ + b) * N_ * F_;
    #pragma unroll
    for (int it = 0; it < 4; ++it)
        #pragma unroll
        for (int ft = 0; ft < 2; ++ft) {
            const int col = w * 32 + ft * 16 + l15;
            #pragma unroll
            for (int rr = 0; rr < 4; ++rr) {
                const int row = i0 + it * 16 + quad * 4 + rr;
                pout[(size_t)row * F_ + col] = acc[it][ft][rr];
            }
        }
}

// ---------------- x + 4-way partial sum + LayerNorm -> fp32 + bf16 -------------
__global__ __launch_bounds__(256) void addln4_kernel(
    const float* __restrict__ X, const float* __restrict__ p,
    const float* __restrict__ g, const float* __restrict__ bta,
    float* __restrict__ outf, unsigned short* __restrict__ outb)
{
    const int row = blockIdx.x;
    const int t = threadIdx.x;
    const size_t idx = (size_t)row * F_ + t;
    const size_t S = (size_t)B_ * N_ * F_;
    const float v = X[idx] + p[idx] + p[idx + S] + p[idx + 2 * S] + p[idx + 3 * S];
    float s1 = v, s2 = v * v;
    #pragma unroll
    for (int off = 32; off > 0; off >>= 1) {
        s1 += __shfl_down(s1, off);
        s2 += __shfl_down(s2, off);
    }
    __shared__ float r1[4], r2[4];
    __shared__ float mu_s, rs_s;
    const int wid = t >> 6, lane = t & 63;
    if (lane == 0) { r1[wid] = s1; r2[wid] = s2; }
    __syncthreads();
    if (t == 0) {
        const float a = r1[0] + r1[1] + r1[2] + r1[3];
        const float q = r2[0] + r2[1] + r2[2] + r2[3];
        const float mu = a * (1.f / F_);
        const float var = q * (1.f / F_) - mu * mu;
        mu_s = mu;
        rs_s = rsqrtf(var + EPSV);
    }
    __syncthreads();
    const float r = (v - mu_s) * rs_s * g[t] + bta[t];
    outf[idx] = r;
    outb[idx] = f2bf(r);
}

// ---------------- residual add + LayerNorm (final) -----------------------------
__global__ __launch_bounds__(256) void addln_kernel(
    const float* __restrict__ X, const float* __restrict__ Y,
    const float* __restrict__ g, const float* __restrict__ bta,
    float* __restrict__ out)
{
    const int row = blockIdx.x;
    const int t = threadIdx.x;
    const size_t idx = (size_t)row * F_ + t;
    const float v = X[idx] + Y[idx];
    float s1 = v, s2 = v * v;
    #pragma unroll
    for (int off = 32; off > 0; off >>= 1) {
        s1 += __shfl_down(s1, off);
        s2 += __shfl_down(s2, off);
    }
    __shared__ float r1[4], r2[4];
    __shared__ float mu_s, rs_s;
    const int wid = t >> 6, lane = t & 63;
    if (lane == 0) { r1[wid] = s1; r2[wid] = s2; }
    __syncthreads();
    if (t == 0) {
        const float a = r1[0] + r1[1] + r1[2] + r1[3];
        const float q = r2[0] + r2[1] + r2[2] + r2[3];
        const float mu = a * (1.f / F_);
        const float var = q * (1.f / F_) - mu * mu;
        mu_s = mu;
        rs_s = rsqrtf(var + EPSV);
    }
    __syncthreads();
    out[idx] = (v - mu_s) * rs_s * g[t] + bta[t];
}

// -------------------------------------------------------------------------------
extern "C" void kernel_launch(void* const* d_in, const int* in_sizes, int n_in,
                              void* d_out, int out_size, void* d_ws, size_t ws_size,
                              hipStream_t stream)
{
    const float* x     = (const float*)d_in[0];
    const int*   adj   = (const int*)d_in[1];
    const float* W1    = (const float*)d_in[2];
    const float* a1    = (const float*)d_in[3];
    const float* W2    = (const float*)d_in[4];
    const float* a2    = (const float*)d_in[5];
    const float* w_ff1 = (const float*)d_in[6];
    const float* b_ff1 = (const float*)d_in[7];
    const float* w_ff2 = (const float*)d_in[8];
    const float* b_ff2 = (const float*)d_in[9];
    const float* g_ln1 = (const float*)d_in[10];
    const float* b_ln1 = (const float*)d_in[11];
    const float* g_ln2 = (const float*)d_in[12];
    const float* b_ln2 = (const float*)d_in[13];
    float* out = (float*)d_out;

    const int Rtot = B_ * N_;             // 8192
    char* wsb = (char*)d_ws;
    float* part  = (float*)wsb;                                  // 32 MB
    float* ln1   = (float*)(wsb + 33554432);                     // 8 MB
    float* ffout = (float*)(wsb + 41943040);                     // 8 MB
    unsigned short* mid  = (unsigned short*)(wsb + 50331648);    // 16 MB
    unsigned short* ln1b = (unsigned short*)(wsb + 67108864);    // 4 MB
    unsigned short* Wht  = (unsigned short*)(wsb + 75497472);    // 4 MB
    unsigned long long* mask = (unsigned long long*)(wsb + 79691776); // 4 MB
    unsigned short* mask16 = (unsigned short*)mask;
    unsigned short* Wt1  = (unsigned short*)(wsb + 83886080);    // 128 KB
    unsigned short* Wt2  = Wt1 + 65536;                          // 128 KB
    unsigned short* Wtf1 = Wt2 + 65536;                          // 512 KB
    unsigned short* Wtf2 = Wtf1 + 262144;                        // 512 KB
    float* WhA1 = (float*)(wsb + 85196800);
    float* WhA2 = WhA1 + 8192;
    float* WhB1 = WhA2 + 8192;
    float* WhB2 = WhB1 + 8192;
    float* Mo   = (float*)(wsb + 85327872);                      // 32 KB
    float* pM   = (float*)(wsb + 85360640);                      // 512 KB
    float* pS   = (float*)(wsb + 85884928);                      // 512 KB

    const dim3 statsG(N_ / 256, SPLIT_, B_);
    const dim3 finG(N_ / 256, B_);
    const dim3 attG(N_ / 64, SPLITJ_, B_);

    // ===== prologue: transpose weights + fused zero of Wh scratch =====
    transp_all_kernel<<<dim3(16, 16, 4), 256, 0, stream>>>(
        W1, W2, w_ff1, w_ff2, Wt1, Wt2, Wtf1, Wtf2, WhA1);

    // ===== GAT layer 1 =====
    gemm32_kernel<<<dim3(2, 256), 256, 0, stream>>>(
        x, Wt1, nullptr, nullptr, Wht, a1, WhA1, WhA2, F_, F_, 0, 0, 0);
    colstats_adj_kernel<<<statsG, 256, 0, stream>>>(adj, mask, WhA1, WhA2, pM, pS);
    colfin2_kernel<<<finG, 256, 0, stream>>>(pM, pS, Mo);
    att_mfma7_kernel<<<attG, 512, 0, stream>>>(mask16, Wht, WhA1, WhA2, Mo, part);

    // ===== GAT layer 2: A = sum of 4 partials, fused in GEMM (mask reused) =====
    gemm32_kernel<<<dim3(2, 256), 256, 0, stream>>>(
        part, Wt2, nullptr, nullptr, Wht, a2, WhB1, WhB2, F_, F_, 0, 2, 0);
    colstats3_kernel<<<statsG, 256, 0, stream>>>(mask, WhB1, WhB2, pM, pS);
    colfin2_kernel<<<finG, 256, 0, stream>>>(pM, pS, Mo);
    att_mfma7_kernel<<<attG, 512, 0, stream>>>(mask16, Wht, WhB1, WhB2, Mo, part);

    // ===== LN1(x + sum of 4 att partials) -> ln1 fp32 + ln1b bf16 =====
    addln4_kernel<<<Rtot, 256, 0, stream>>>(x, part, g_ln1, b_ln1, ln1, ln1b);

    // ===== FFN =====
    gemm128_kernel<<<dim3(8, 64), 256, 0, stream>>>(
        ln1b, Wtf1, b_ff1, mid, nullptr, nullptr, nullptr, nullptr, H_, F_, 1, 1, 2);
    gemm32_kernel<<<dim3(2, 256), 256, 0, stream>>>(
        mid, Wtf2, b_ff2, ffout, nullptr, nullptr, nullptr, nullptr, F_, H_, 0, 1, 1);

    // ===== LN2(ln1 + ff) =====
    addln_kernel<<<Rtot, 256, 0, stream>>>(ln1, ffout, g_ln2, b_ln2, out);
}